// Round 5
// baseline (961.762 us; speedup 1.0000x reference)
//
#include <hip/hip_runtime.h>

#define HW    4096
#define WIMG  64
#define CIN   256
#define C3    768
#define COUT  256
#define BATCH 16
#define NHB   32
#define EPS_F 1e-5f
#define QSCALE 1024.0f   // pow2: exactly undone in epilogue

typedef __attribute__((ext_vector_type(8))) short    short8;
typedef __attribute__((ext_vector_type(8))) _Float16 half8;
typedef __attribute__((ext_vector_type(4))) float    floatx4;

__device__ inline short f32_to_bf16(float f) {
    unsigned u = __builtin_bit_cast(unsigned, f);
    unsigned r = u + 0x7fffu + ((u >> 16) & 1u);
    return (short)(r >> 16);
}
__device__ inline float bf16_to_f32(short s) {
    return __builtin_bit_cast(float, ((unsigned)(unsigned short)s) << 16);
}

// ---------------------------------------------------------------------------
// K1a: q channels (packed 256) of qkv 1x1 conv, f32 VALU GEMM.
// 128x128 tile, 8x8 per thread (split as {t*4, 64+t*4} for 2-way-free LDS).
// q needs f32 absolute accuracy (eps-denominator cliff).
// Packed c' in [0,256): real C3 channel = (c'>>3)*24 + (c'&7).
// ---------------------------------------------------------------------------
__global__ __launch_bounds__(256) void conv_q_f32(
    const float* __restrict__ in,     // (B, 256, HW)
    const float* __restrict__ w,      // (768, 256)
    const float* __restrict__ scale,
    const float* __restrict__ bias,
    float* __restrict__ Qf)           // (B, 256, HW) packed q
{
    const int pt  = blockIdx.x * 128;
    const int ct  = blockIdx.y * 128;
    const int b   = blockIdx.z;
    const int tid = threadIdx.x;
    const int tx  = tid & 15;         // px groups tx*4 and 64+tx*4
    const int ty  = tid >> 4;         // ch groups ty*4 and 64+ty*4

    __shared__ float Ws[16][128];
    __shared__ float Xs[16][128];

    float acc[8][8] = {};
    const float* xb = in + (size_t)b * CIN * HW + pt;

    for (int k0 = 0; k0 < CIN; k0 += 16) {
        #pragma unroll
        for (int i = 0; i < 8; i++) {
            int idx = tid + i * 256;          // 0..2047
            int c = idx >> 4, k = idx & 15;
            int cp = ct + c;
            int creal = (cp >> 3) * 24 + (cp & 7);
            Ws[k][c] = w[(size_t)creal * CIN + k0 + k];
        }
        #pragma unroll
        for (int i = 0; i < 8; i++) {
            int idx = tid + i * 256;
            int k = idx >> 7, p = idx & 127;
            Xs[k][p] = xb[(size_t)(k0 + k) * HW + p];
        }
        __syncthreads();
        #pragma unroll
        for (int kk = 0; kk < 16; kk++) {
            float4 a0 = *reinterpret_cast<const float4*>(&Ws[kk][ty * 4]);
            float4 a1 = *reinterpret_cast<const float4*>(&Ws[kk][64 + ty * 4]);
            float4 b0 = *reinterpret_cast<const float4*>(&Xs[kk][tx * 4]);
            float4 b1 = *reinterpret_cast<const float4*>(&Xs[kk][64 + tx * 4]);
            float a[8] = {a0.x, a0.y, a0.z, a0.w, a1.x, a1.y, a1.z, a1.w};
            float bb[8] = {b0.x, b0.y, b0.z, b0.w, b1.x, b1.y, b1.z, b1.w};
            #pragma unroll
            for (int i = 0; i < 8; i++)
                #pragma unroll
                for (int j = 0; j < 8; j++)
                    acc[i][j] += a[i] * bb[j];
        }
        __syncthreads();
    }

    #pragma unroll
    for (int i = 0; i < 8; i++) {
        int cp = ct + (i < 4 ? ty * 4 + i : 64 + ty * 4 + (i - 4));
        int creal = (cp >> 3) * 24 + (cp & 7);
        float s = scale[creal];
        float bi = bias[creal];
        float4 v0, v1;
        v0.x = fmaxf(acc[i][0] * s + bi, 0.f);
        v0.y = fmaxf(acc[i][1] * s + bi, 0.f);
        v0.z = fmaxf(acc[i][2] * s + bi, 0.f);
        v0.w = fmaxf(acc[i][3] * s + bi, 0.f);
        v1.x = fmaxf(acc[i][4] * s + bi, 0.f);
        v1.y = fmaxf(acc[i][5] * s + bi, 0.f);
        v1.z = fmaxf(acc[i][6] * s + bi, 0.f);
        v1.w = fmaxf(acc[i][7] * s + bi, 0.f);
        float* dst = Qf + ((size_t)b * 256 + cp) * HW + pt;
        *reinterpret_cast<float4*>(dst + tx * 4)      = v0;
        *reinterpret_cast<float4*>(dst + 64 + tx * 4) = v1;
    }
}

// ---------------------------------------------------------------------------
// K1b: k/v channels (packed 512) via bf16 hi/lo 3-pass MFMA (~f32 accurate).
// Packed c' in [0,512): real = (c'>>4)*24 + 8 + (c'&15). Out f32.
// ---------------------------------------------------------------------------
__global__ __launch_bounds__(256) void conv_kv_mfma(
    const float* __restrict__ x,
    const float* __restrict__ w,
    const float* __restrict__ scale,
    const float* __restrict__ bias,
    float* __restrict__ KV)           // (B, 512, HW) packed k/v, f32
{
    const int ct = blockIdx.x, pt = blockIdx.y, b = blockIdx.z;
    const int tid  = threadIdx.x;
    const int wv   = tid >> 6, lane = tid & 63;
    const int u    = lane & 15, q8 = (lane >> 4) * 8;
    const int chb  = ct * 128 + (wv >> 1) * 64;
    const int pxb  = pt * 128 + (wv & 1) * 64;

    floatx4 acc[4][4];
    #pragma unroll
    for (int i = 0; i < 4; i++)
        #pragma unroll
        for (int j = 0; j < 4; j++) acc[i][j] = (floatx4)0.f;

    for (int kc = 0; kc < 8; kc++) {
        const int k0 = kc * 32 + q8;
        short8 ahi[4], alo[4];
        #pragma unroll
        for (int mt = 0; mt < 4; mt++) {
            int cp = chb + mt * 16 + u;
            int creal = (cp >> 4) * 24 + 8 + (cp & 15);
            const float* wp = w + (size_t)creal * CIN + k0;
            #pragma unroll
            for (int j = 0; j < 8; j++) {
                float f = wp[j];
                short h = f32_to_bf16(f);
                ahi[mt][j] = h;
                alo[mt][j] = f32_to_bf16(f - bf16_to_f32(h));
            }
        }
        short8 bhi[4], blo[4];
        #pragma unroll
        for (int nt = 0; nt < 4; nt++) {
            const float* xp = x + ((size_t)b * CIN + k0) * HW + pxb + nt * 16 + u;
            #pragma unroll
            for (int j = 0; j < 8; j++) {
                float f = xp[(size_t)j * HW];
                short h = f32_to_bf16(f);
                bhi[nt][j] = h;
                blo[nt][j] = f32_to_bf16(f - bf16_to_f32(h));
            }
        }
        #pragma unroll
        for (int mt = 0; mt < 4; mt++)
            #pragma unroll
            for (int nt = 0; nt < 4; nt++) {
                acc[mt][nt] = __builtin_amdgcn_mfma_f32_16x16x32_bf16(ahi[mt], bhi[nt], acc[mt][nt], 0, 0, 0);
                acc[mt][nt] = __builtin_amdgcn_mfma_f32_16x16x32_bf16(ahi[mt], blo[nt], acc[mt][nt], 0, 0, 0);
                acc[mt][nt] = __builtin_amdgcn_mfma_f32_16x16x32_bf16(alo[mt], bhi[nt], acc[mt][nt], 0, 0, 0);
            }
    }

    const int quad = lane >> 4;
    #pragma unroll
    for (int mt = 0; mt < 4; mt++)
        #pragma unroll
        for (int r = 0; r < 4; r++) {
            int cp = chb + mt * 16 + quad * 4 + r;
            int creal = (cp >> 4) * 24 + 8 + (cp & 15);
            float s = scale[creal], bi = bias[creal];
            #pragma unroll
            for (int nt = 0; nt < 4; nt++) {
                int px = pxb + nt * 16 + u;
                KV[((size_t)b * 512 + cp) * HW + px] = fmaxf(acc[mt][nt][r] * s + bi, 0.f);
            }
        }
}

// ---------------------------------------------------------------------------
// K0z: zero the stats region (atomic consumers below; re-entrant per launch).
// ---------------------------------------------------------------------------
__global__ __launch_bounds__(256) void zero_stats(float* __restrict__ stats)
{
    int i = blockIdx.x * 256 + threadIdx.x;
    if (i < BATCH * 64 * 72) stats[i] = 0.f;
}

// ---------------------------------------------------------------------------
// K2: stats heads 0..31, direct from KV f32.
// Split over 4 pixel chunks (1024 px each) -> 2048 blocks; atomic reduce.
// ---------------------------------------------------------------------------
__global__ __launch_bounds__(256) void attn_stats_direct(
    const float* __restrict__ KV,
    float* __restrict__ stats)
{
    const int h = blockIdx.x, ps = blockIdx.y, b = blockIdx.z;
    const int tid = threadIdx.x;
    const int lane = tid & 63, wave = tid >> 6;

    const float* src = KV + ((size_t)b * 512 + h * 16) * HW + ps * 1024;

    float acc[72];
    #pragma unroll
    for (int i = 0; i < 72; i++) acc[i] = 0.f;

    for (int p = tid; p < 1024; p += 256) {
        float kv[8], vv[8];
        #pragma unroll
        for (int e = 0; e < 8; e++) kv[e] = fmaxf(src[(size_t)e * HW + p], 0.f);
        #pragma unroll
        for (int d = 0; d < 8; d++) vv[d] = src[(size_t)(8 + d) * HW + p];
        #pragma unroll
        for (int d = 0; d < 8; d++)
            #pragma unroll
            for (int e = 0; e < 8; e++)
                acc[d * 8 + e] += vv[d] * kv[e];
        #pragma unroll
        for (int e = 0; e < 8; e++) acc[64 + e] += kv[e];
    }

    __shared__ float red[4][72];
    #pragma unroll
    for (int i = 0; i < 72; i++) {
        float v = acc[i];
        v += __shfl_down(v, 32); v += __shfl_down(v, 16); v += __shfl_down(v, 8);
        v += __shfl_down(v, 4);  v += __shfl_down(v, 2);  v += __shfl_down(v, 1);
        if (lane == 0) red[wave][i] = v;
    }
    __syncthreads();
    if (tid < 72)
        atomicAdd(&stats[((size_t)b * 64 + h) * 72 + tid],
                  red[0][tid] + red[1][tid] + red[2][tid] + red[3][tid]);
}

// ---------------------------------------------------------------------------
// K3 v5: stats heads 32..63, fused depthwise 5x5 + affine from KV f32.
// NO LDS staging, NO barriers: each thread computes a 2x2 px patch reading
// taps directly from global (L2-resident, ~4.5x neighbor reuse). Row y
// clamped for address safety; zeroing via branchless masks (hoisted cmps).
// Uniform per-ch SGPR base + VGPR row offset -> minimal address VALU.
// grid (32 hp, 4 ysb, 16 b) = 2048 blocks; only red[] LDS (1.2 KB) ->
// occupancy VGPR-bound (~3 waves/SIMD). Atomic reduce into stats.
// ---------------------------------------------------------------------------
__global__ __launch_bounds__(256) void attn_stats_dw(
    const float* __restrict__ KV,
    const float* __restrict__ dww, const float* __restrict__ dwb,
    const float* __restrict__ pww, const float* __restrict__ pwb,
    float* __restrict__ stats)
{
    const int hp = blockIdx.x, ysb = blockIdx.y, b = blockIdx.z;
    const int tid = threadIdx.x;
    const int lane = tid & 63, wave = tid >> 6;
    const int base = hp * 24 + 8;

    const int x0 = (tid & 31) * 2;          // 2 px wide
    const int y0 = ysb * 16 + (tid >> 5) * 2; // 2 px tall

    const bool lok = (x0 != 0);             // left float2 valid
    const bool rok = (x0 != 62);            // right float2 valid
    const int dx0 = lok ? -2 : 0;           // clamp addr; value masked
    const int dx2 = rok ?  2 : 0;

    int  yrx[6];                            // clamped row offset + x0
    bool yok[6];
    #pragma unroll
    for (int r = 0; r < 6; r++) {
        int y = y0 - 2 + r;
        yok[r] = (y >= 0) && (y < WIMG);
        int yc = y < 0 ? 0 : (y > WIMG - 1 ? WIMG - 1 : y);
        yrx[r] = yc * WIMG + x0;
    }

    const float* kvb = KV + ((size_t)b * 512 + hp * 16) * HW;

    float acc[72];
    #pragma unroll
    for (int i = 0; i < 72; i++) acc[i] = 0.f;
    float kv[2][2][8];                      // [oy][ox][e] relu'd k-agg

    // ---- phase A: k channels 0..7 ----
    #pragma unroll
    for (int ch = 0; ch < 8; ch++) {
        const int c = base + ch;
        const float* wr = &dww[c * 25];
        const float* cb = kvb + (size_t)ch * HW;   // uniform base
        float s00 = 0.f, s01 = 0.f, s10 = 0.f, s11 = 0.f;
        #pragma unroll
        for (int r = 0; r < 6; r++) {
            const float* rp = cb + yrx[r];
            float2 L0 = *reinterpret_cast<const float2*>(rp + dx0);
            float2 L1 = *reinterpret_cast<const float2*>(rp);
            float2 L2 = *reinterpret_cast<const float2*>(rp + dx2);
            float r6[6];
            r6[0] = (yok[r] && lok) ? L0.x : 0.f;
            r6[1] = (yok[r] && lok) ? L0.y : 0.f;
            r6[2] = yok[r] ? L1.x : 0.f;
            r6[3] = yok[r] ? L1.y : 0.f;
            r6[4] = (yok[r] && rok) ? L2.x : 0.f;
            r6[5] = (yok[r] && rok) ? L2.y : 0.f;
            if (r < 5) {                    // out row 0, ky = r
                #pragma unroll
                for (int kx = 0; kx < 5; kx++) {
                    float wt = wr[r * 5 + kx];
                    s00 += wt * r6[kx];
                    s01 += wt * r6[kx + 1];
                }
            }
            if (r > 0) {                    // out row 1, ky = r-1
                #pragma unroll
                for (int kx = 0; kx < 5; kx++) {
                    float wt = wr[(r - 1) * 5 + kx];
                    s10 += wt * r6[kx];
                    s11 += wt * r6[kx + 1];
                }
            }
        }
        float pw = pww[c];
        float pb = pw * dwb[c] + pwb[c];
        kv[0][0][ch] = fmaxf(s00 * pw + pb, 0.f);
        kv[0][1][ch] = fmaxf(s01 * pw + pb, 0.f);
        kv[1][0][ch] = fmaxf(s10 * pw + pb, 0.f);
        kv[1][1][ch] = fmaxf(s11 * pw + pb, 0.f);
    }
    #pragma unroll
    for (int e = 0; e < 8; e++)
        acc[64 + e] += kv[0][0][e] + kv[0][1][e] + kv[1][0][e] + kv[1][1][e];

    // ---- phase B: v channels 8..15, fold outer product ----
    #pragma unroll
    for (int d = 0; d < 8; d++) {
        const int c = base + 8 + d;
        const float* wr = &dww[c * 25];
        const float* cb = kvb + (size_t)(8 + d) * HW;
        float s00 = 0.f, s01 = 0.f, s10 = 0.f, s11 = 0.f;
        #pragma unroll
        for (int r = 0; r < 6; r++) {
            const float* rp = cb + yrx[r];
            float2 L0 = *reinterpret_cast<const float2*>(rp + dx0);
            float2 L1 = *reinterpret_cast<const float2*>(rp);
            float2 L2 = *reinterpret_cast<const float2*>(rp + dx2);
            float r6[6];
            r6[0] = (yok[r] && lok) ? L0.x : 0.f;
            r6[1] = (yok[r] && lok) ? L0.y : 0.f;
            r6[2] = yok[r] ? L1.x : 0.f;
            r6[3] = yok[r] ? L1.y : 0.f;
            r6[4] = (yok[r] && rok) ? L2.x : 0.f;
            r6[5] = (yok[r] && rok) ? L2.y : 0.f;
            if (r < 5) {
                #pragma unroll
                for (int kx = 0; kx < 5; kx++) {
                    float wt = wr[r * 5 + kx];
                    s00 += wt * r6[kx];
                    s01 += wt * r6[kx + 1];
                }
            }
            if (r > 0) {
                #pragma unroll
                for (int kx = 0; kx < 5; kx++) {
                    float wt = wr[(r - 1) * 5 + kx];
                    s10 += wt * r6[kx];
                    s11 += wt * r6[kx + 1];
                }
            }
        }
        float pw = pww[c];
        float pb = pw * dwb[c] + pwb[c];
        float v00 = s00 * pw + pb, v01 = s01 * pw + pb;
        float v10 = s10 * pw + pb, v11 = s11 * pw + pb;
        #pragma unroll
        for (int e = 0; e < 8; e++)
            acc[d * 8 + e] += v00 * kv[0][0][e] + v01 * kv[0][1][e]
                            + v10 * kv[1][0][e] + v11 * kv[1][1][e];
    }

    __shared__ float red[4][72];
    #pragma unroll
    for (int i = 0; i < 72; i++) {
        float v = acc[i];
        v += __shfl_down(v, 32); v += __shfl_down(v, 16); v += __shfl_down(v, 8);
        v += __shfl_down(v, 4);  v += __shfl_down(v, 2);  v += __shfl_down(v, 1);
        if (lane == 0) red[wave][i] = v;
    }
    __syncthreads();
    if (tid < 72)
        atomicAdd(&stats[((size_t)b * 64 + 32 + hp) * 72 + tid],
                  red[0][tid] + red[1][tid] + red[2][tid] + red[3][tid]);
}

// ---------------------------------------------------------------------------
// K3b v5: Qagg = depthwise 5x5 + affine of q channels, direct-global reads,
// no LDS/barriers. Same 2x2-patch structure as K3 v5. grid (32,4,16).
// Disjoint float2 stores, no atomics. Raw output (relu in K5).
// ---------------------------------------------------------------------------
__global__ __launch_bounds__(256) void q_dwconv(
    const float* __restrict__ Qf,     // (B,256,HW) packed q
    const float* __restrict__ dww, const float* __restrict__ dwb,
    const float* __restrict__ pww, const float* __restrict__ pwb,
    float* __restrict__ Qagg)         // (B,256,HW) packed dwconv(q)
{
    const int hb = blockIdx.x, ysb = blockIdx.y, b = blockIdx.z;
    const int tid = threadIdx.x;

    const int x0 = (tid & 31) * 2;
    const int y0 = ysb * 16 + (tid >> 5) * 2;

    const bool lok = (x0 != 0);
    const bool rok = (x0 != 62);
    const int dx0 = lok ? -2 : 0;
    const int dx2 = rok ?  2 : 0;

    int  yrx[6];
    bool yok[6];
    #pragma unroll
    for (int r = 0; r < 6; r++) {
        int y = y0 - 2 + r;
        yok[r] = (y >= 0) && (y < WIMG);
        int yc = y < 0 ? 0 : (y > WIMG - 1 ? WIMG - 1 : y);
        yrx[r] = yc * WIMG + x0;
    }

    const float* qb = Qf + ((size_t)b * 256 + hb * 8) * HW;

    #pragma unroll
    for (int ch = 0; ch < 8; ch++) {
        const int c = hb * 24 + ch;            // real C3 channel (q of agg)
        const float* wr = &dww[c * 25];
        const float* cb = qb + (size_t)ch * HW;
        float s00 = 0.f, s01 = 0.f, s10 = 0.f, s11 = 0.f;
        #pragma unroll
        for (int r = 0; r < 6; r++) {
            const float* rp = cb + yrx[r];
            float2 L0 = *reinterpret_cast<const float2*>(rp + dx0);
            float2 L1 = *reinterpret_cast<const float2*>(rp);
            float2 L2 = *reinterpret_cast<const float2*>(rp + dx2);
            float r6[6];
            r6[0] = (yok[r] && lok) ? L0.x : 0.f;
            r6[1] = (yok[r] && lok) ? L0.y : 0.f;
            r6[2] = yok[r] ? L1.x : 0.f;
            r6[3] = yok[r] ? L1.y : 0.f;
            r6[4] = (yok[r] && rok) ? L2.x : 0.f;
            r6[5] = (yok[r] && rok) ? L2.y : 0.f;
            if (r < 5) {
                #pragma unroll
                for (int kx = 0; kx < 5; kx++) {
                    float wt = wr[r * 5 + kx];
                    s00 += wt * r6[kx];
                    s01 += wt * r6[kx + 1];
                }
            }
            if (r > 0) {
                #pragma unroll
                for (int kx = 0; kx < 5; kx++) {
                    float wt = wr[(r - 1) * 5 + kx];
                    s10 += wt * r6[kx];
                    s11 += wt * r6[kx + 1];
                }
            }
        }
        float pw = pww[c];
        float pb = pw * dwb[c] + pwb[c];
        float* dst = Qagg + ((size_t)b * 256 + hb * 8 + ch) * HW + y0 * WIMG + x0;
        float2 o0 = {s00 * pw + pb, s01 * pw + pb};
        float2 o1 = {s10 * pw + pb, s11 * pw + pb};
        *reinterpret_cast<float2*>(dst)         = o0;
        *reinterpret_cast<float2*>(dst + WIMG)  = o1;
    }
}

// ---------------------------------------------------------------------------
// K4: fold proj weights with vk, COLUMN-RESCALED by g_e = ksum_e + eps:
// M'[b][c][h*8+e] = (sum_d w[c][h*8+d]*vk[h][d][e]) / g_{h,e}. f16 hi/lo.
// ---------------------------------------------------------------------------
__global__ __launch_bounds__(256) void build_M(
    const float* __restrict__ stats,   // (B,64,72)
    const float* __restrict__ projw,   // (256,512)
    _Float16* __restrict__ Mhi,        // (B,256,512)
    _Float16* __restrict__ Mlo)
{
    const int b = blockIdx.x;
    const int tid = threadIdx.x;
    __shared__ float svk[64][64];
    __shared__ float sginv[64][8];
    for (int i = tid; i < 64 * 64; i += 256)
        svk[i >> 6][i & 63] = stats[((size_t)b * 64 + (i >> 6)) * 72 + (i & 63)];
    for (int i = tid; i < 512; i += 256)
        sginv[i >> 3][i & 7] =
            1.0f / (stats[((size_t)b * 64 + (i >> 3)) * 72 + 64 + (i & 7)] + EPS_F);
    __syncthreads();

    const float* wr = projw + (size_t)tid * 512;
    for (int h = 0; h < 64; h++) {
        float wv[8];
        float4 a0 = *reinterpret_cast<const float4*>(wr + h * 8);
        float4 a1 = *reinterpret_cast<const float4*>(wr + h * 8 + 4);
        wv[0]=a0.x; wv[1]=a0.y; wv[2]=a0.z; wv[3]=a0.w;
        wv[4]=a1.x; wv[5]=a1.y; wv[6]=a1.z; wv[7]=a1.w;
        union { _Float16 h8[8]; uint4 u; } hi, lo;
        #pragma unroll
        for (int e = 0; e < 8; e++) {
            float s = 0.f;
            #pragma unroll
            for (int d = 0; d < 8; d++) s += wv[d] * svk[h][d * 8 + e];
            s *= sginv[h][e];
            _Float16 sh = (_Float16)s;
            hi.h8[e] = sh;
            lo.h8[e] = (_Float16)(s - (float)sh);
        }
        *reinterpret_cast<uint4*>(Mhi + ((size_t)b * 256 + tid) * 512 + h * 8) = hi.u;
        *reinterpret_cast<uint4*>(Mlo + ((size_t)b * 256 + tid) * 512 + h * 8) = lo.u;
    }
}

// ---------------------------------------------------------------------------
// K5: 128-px tile, 4 barriers total. Qt_e = QSCALE*g_e*q_e/den (bounded),
// f16; two half-K phases (heads 0..31 from Qf, 32..63 from Qagg), each a
// 2-pass hi/lo f16 MFMA GEMM (256ch x 128px). LDS ~70 KB -> 2 blocks/CU.
// ---------------------------------------------------------------------------
__global__ __launch_bounds__(256) void attn_proj_mfma(
    const float* __restrict__ Qf,      // (B,256,HW) packed q (>=0)
    const float* __restrict__ Qagg,    // (B,256,HW) packed dwconv(q), raw
    const float* __restrict__ stats,   // ksum at [64..71]
    const _Float16* __restrict__ Mhi,  // (B,256,512)
    const _Float16* __restrict__ Mlo,
    const float* __restrict__ scale, const float* __restrict__ bias,
    float* __restrict__ out)           // (B,256,HW)
{
    const int pt  = blockIdx.x * 128;
    const int b   = blockIdx.y;
    const int tid = threadIdx.x;
    const int wv  = tid >> 6, lane = tid & 63;

    __shared__ _Float16 Qt[128][264];     // 67.6 KB half-K [px][k]
    __shared__ float    ksums[64][8];     // 2 KB

    for (int i = tid; i < 512; i += 256)
        ksums[i >> 3][i & 7] = stats[((size_t)b * 64 + (i >> 3)) * 72 + 64 + (i & 7)];
    __syncthreads();

    const int pxl = tid & 127;            // local pixel for Qt build
    const int eg  = (tid >> 7) * 4;       // 4 e's per thread
    const int u = lane & 15, q8 = (lane >> 4) * 8;
    const int quad = lane >> 4;

    floatx4 acc[4][8];
    #pragma unroll
    for (int i = 0; i < 4; i++)
        #pragma unroll
        for (int j = 0; j < 8; j++) acc[i][j] = (floatx4)0.f;

    // ============ phase A: heads 0..31 (q direct from Qf, >=0) ============
    for (int h = 0; h < 32; h++) {
        const float* qp = Qf + ((size_t)b * 256 + h * 8) * HW + pt + pxl;
        float qv[8];
        #pragma unroll
        for (int e = 0; e < 8; e++) qv[e] = qp[(size_t)e * HW];
        float den = EPS_F;
        #pragma unroll
        for (int e = 0; e < 8; e++) den += ksums[h][e] * qv[e];
        float rd = QSCALE / den;
        union { _Float16 h4[4]; uint2 u2; } pk;
        #pragma unroll
        for (int j = 0; j < 4; j++) {
            float g = ksums[h][eg + j] + EPS_F;
            pk.h4[j] = (_Float16)fminf(qv[eg + j] * g * rd, 60000.f);
        }
        *reinterpret_cast<uint2*>(&Qt[pxl][h * 8 + eg]) = pk.u2;
    }
    __syncthreads();

    for (int ks = 0; ks < 8; ks++) {
        half8 ah[4], al[4], bf[8];
        #pragma unroll
        for (int mt = 0; mt < 4; mt++) {
            size_t moff = ((size_t)b * 256 + wv * 64 + mt * 16 + u) * 512 + ks * 32 + q8;
            ah[mt] = *reinterpret_cast<const half8*>(Mhi + moff);
            al[mt] = *reinterpret_cast<const half8*>(Mlo + moff);
        }
        #pragma unroll
        for (int nt = 0; nt < 8; nt++)
            bf[nt] = *reinterpret_cast<const half8*>(&Qt[nt * 16 + u][ks * 32 + q8]);
        #pragma unroll
        for (int mt = 0; mt < 4; mt++)
            #pragma unroll
            for (int nt = 0; nt < 8; nt++) {
                acc[mt][nt] = __builtin_amdgcn_mfma_f32_16x16x32_f16(ah[mt], bf[nt], acc[mt][nt], 0, 0, 0);
                acc[mt][nt] = __builtin_amdgcn_mfma_f32_16x16x32_f16(al[mt], bf[nt], acc[mt][nt], 0, 0, 0);
            }
    }
    __syncthreads();

    // ============ phase B: heads 32..63 (q from Qagg, needs relu) ==========
    for (int h = 32; h < 64; h++) {
        const int hb = h - 32;
        const float* qp = Qagg + ((size_t)b * 256 + hb * 8) * HW + pt + pxl;
        float qv[8];
        #pragma unroll
        for (int e = 0; e < 8; e++) qv[e] = fmaxf(qp[(size_t)e * HW], 0.f);
        float den = EPS_F;
        #pragma unroll
        for (int e = 0; e < 8; e++) den += ksums[h][e] * qv[e];
        float rd = QSCALE / den;
        union { _Float16 h4[4]; uint2 u2; } pk;
        #pragma unroll
        for (int j = 0; j < 4; j++) {
            float g = ksums[h][eg + j] + EPS_F;
            pk.h4[j] = (_Float16)fminf(qv[eg + j] * g * rd, 60000.f);
        }
        *reinterpret_cast<uint2*>(&Qt[pxl][hb * 8 + eg]) = pk.u2;
    }
    __syncthreads();

    for (int ks = 0; ks < 8; ks++) {
        half8 ah[4], al[4], bf[8];
        #pragma unroll
        for (int mt = 0; mt < 4; mt++) {
            size_t moff = ((size_t)b * 256 + wv * 64 + mt * 16 + u) * 512 + 256 + ks * 32 + q8;
            ah[mt] = *reinterpret_cast<const half8*>(Mhi + moff);
            al[mt] = *reinterpret_cast<const half8*>(Mlo + moff);
        }
        #pragma unroll
        for (int nt = 0; nt < 8; nt++)
            bf[nt] = *reinterpret_cast<const half8*>(&Qt[nt * 16 + u][ks * 32 + q8]);
        #pragma unroll
        for (int mt = 0; mt < 4; mt++)
            #pragma unroll
            for (int nt = 0; nt < 8; nt++) {
                acc[mt][nt] = __builtin_amdgcn_mfma_f32_16x16x32_f16(ah[mt], bf[nt], acc[mt][nt], 0, 0, 0);
                acc[mt][nt] = __builtin_amdgcn_mfma_f32_16x16x32_f16(al[mt], bf[nt], acc[mt][nt], 0, 0, 0);
            }
    }

    #pragma unroll
    for (int mt = 0; mt < 4; mt++)
        #pragma unroll
        for (int r = 0; r < 4; r++) {
            int c = wv * 64 + mt * 16 + quad * 4 + r;
            float s = scale[c] * (1.0f / QSCALE);
            float bi = bias[c];
            #pragma unroll
            for (int nt = 0; nt < 8; nt++) {
                int px = pt + nt * 16 + u;
                out[((size_t)b * COUT + c) * HW + px] = fmaxf(acc[mt][nt][r] * s + bi, 0.f);
            }
        }
}

// ---------------------------------------------------------------------------
extern "C" void kernel_launch(void* const* d_in, const int* in_sizes, int n_in,
                              void* d_out, int out_size, void* d_ws, size_t ws_size,
                              hipStream_t stream)
{
    const float* x      = (const float*)d_in[0];
    const float* qkv_w  = (const float*)d_in[1];
    const float* qkv_s  = (const float*)d_in[2];
    const float* qkv_b  = (const float*)d_in[3];
    const float* dw_w   = (const float*)d_in[4];
    const float* dw_b   = (const float*)d_in[5];
    const float* pw_w   = (const float*)d_in[6];
    const float* pw_b   = (const float*)d_in[7];
    const float* proj_w = (const float*)d_in[8];
    const float* proj_s = (const float*)d_in[9];
    const float* proj_b = (const float*)d_in[10];
    float* out = (float*)d_out;

    // ws layout (exactly the PROVEN 192.3 MiB):
    //   [0,128 MiB)    KV f32 — dead after K2/K3; reused: Mhi(4)+Mlo(4)+Qagg(64)
    //   [128,192 MiB)  Qf f32
    //   [192 MiB,+288K) stats
    float*    KV    = (float*)d_ws;
    _Float16* Mhi   = (_Float16*)d_ws;                          // +0
    _Float16* Mlo   = Mhi + (size_t)BATCH * 256 * 512;          // +4 MiB
    float*    Qagg  = (float*)(Mlo + (size_t)BATCH * 256 * 512);// +8 MiB (64 MiB)
    float*    Qf    = KV + (size_t)BATCH * 512 * HW;            // +128 MiB
    float*    stats = Qf + (size_t)BATCH * 256 * HW;            // +192 MiB

    conv_q_f32<<<dim3(HW / 128, 2, BATCH), 256, 0, stream>>>(
        x, qkv_w, qkv_s, qkv_b, Qf);

    conv_kv_mfma<<<dim3(4, 32, BATCH), 256, 0, stream>>>(
        x, qkv_w, qkv_s, qkv_b, KV);

    // zero stats before the atomic-reduce stats kernels
    zero_stats<<<dim3((BATCH * 64 * 72 + 255) / 256), 256, 0, stream>>>(stats);

    attn_stats_direct<<<dim3(32, 4, BATCH), 256, 0, stream>>>(KV, stats);

    attn_stats_dw<<<dim3(32, 4, BATCH), 256, 0, stream>>>(
        KV, dw_w, dw_b, pw_w, pw_b, stats);

    // after K2/K3: KV region dead -> safe to overwrite with Qagg / M
    q_dwconv<<<dim3(32, 4, BATCH), 256, 0, stream>>>(
        Qf, dw_w, dw_b, pw_w, pw_b, Qagg);

    build_M<<<dim3(BATCH), 256, 0, stream>>>(stats, proj_w, Mhi, Mlo);

    attn_proj_mfma<<<dim3(HW / 128, BATCH), 256, 0, stream>>>(
        Qf, Qagg, stats, Mhi, Mlo, proj_s, proj_b, out);
}

// Round 6
// 894.366 us; speedup vs baseline: 1.0754x; 1.0754x over previous
//
#include <hip/hip_runtime.h>

#define HW    4096
#define WIMG  64
#define CIN   256
#define C3    768
#define COUT  256
#define BATCH 16
#define NHB   32
#define EPS_F 1e-5f
#define QSCALE 1024.0f   // pow2: exactly undone in epilogue

typedef __attribute__((ext_vector_type(8))) short    short8;
typedef __attribute__((ext_vector_type(8))) _Float16 half8;
typedef __attribute__((ext_vector_type(4))) float    floatx4;

__device__ inline short f32_to_bf16(float f) {
    unsigned u = __builtin_bit_cast(unsigned, f);
    unsigned r = u + 0x7fffu + ((u >> 16) & 1u);
    return (short)(r >> 16);
}
__device__ inline float bf16_to_f32(short s) {
    return __builtin_bit_cast(float, ((unsigned)(unsigned short)s) << 16);
}

// ---------------------------------------------------------------------------
// K1a: q channels (packed 256) of qkv 1x1 conv, f32 VALU GEMM.
// 128x128 tile, 8x8 per thread (split as {t*4, 64+t*4} for 2-way-free LDS).
// q needs f32 absolute accuracy (eps-denominator cliff).
// Packed c' in [0,256): real C3 channel = (c'>>3)*24 + (c'&7).
// ---------------------------------------------------------------------------
__global__ __launch_bounds__(256) void conv_q_f32(
    const float* __restrict__ in,     // (B, 256, HW)
    const float* __restrict__ w,      // (768, 256)
    const float* __restrict__ scale,
    const float* __restrict__ bias,
    float* __restrict__ Qf)           // (B, 256, HW) packed q
{
    const int pt  = blockIdx.x * 128;
    const int ct  = blockIdx.y * 128;
    const int b   = blockIdx.z;
    const int tid = threadIdx.x;
    const int tx  = tid & 15;         // px groups tx*4 and 64+tx*4
    const int ty  = tid >> 4;         // ch groups ty*4 and 64+ty*4

    __shared__ float Ws[16][128];
    __shared__ float Xs[16][128];

    float acc[8][8] = {};
    const float* xb = in + (size_t)b * CIN * HW + pt;

    for (int k0 = 0; k0 < CIN; k0 += 16) {
        #pragma unroll
        for (int i = 0; i < 8; i++) {
            int idx = tid + i * 256;          // 0..2047
            int c = idx >> 4, k = idx & 15;
            int cp = ct + c;
            int creal = (cp >> 3) * 24 + (cp & 7);
            Ws[k][c] = w[(size_t)creal * CIN + k0 + k];
        }
        #pragma unroll
        for (int i = 0; i < 8; i++) {
            int idx = tid + i * 256;
            int k = idx >> 7, p = idx & 127;
            Xs[k][p] = xb[(size_t)(k0 + k) * HW + p];
        }
        __syncthreads();
        #pragma unroll
        for (int kk = 0; kk < 16; kk++) {
            float4 a0 = *reinterpret_cast<const float4*>(&Ws[kk][ty * 4]);
            float4 a1 = *reinterpret_cast<const float4*>(&Ws[kk][64 + ty * 4]);
            float4 b0 = *reinterpret_cast<const float4*>(&Xs[kk][tx * 4]);
            float4 b1 = *reinterpret_cast<const float4*>(&Xs[kk][64 + tx * 4]);
            float a[8] = {a0.x, a0.y, a0.z, a0.w, a1.x, a1.y, a1.z, a1.w};
            float bb[8] = {b0.x, b0.y, b0.z, b0.w, b1.x, b1.y, b1.z, b1.w};
            #pragma unroll
            for (int i = 0; i < 8; i++)
                #pragma unroll
                for (int j = 0; j < 8; j++)
                    acc[i][j] += a[i] * bb[j];
        }
        __syncthreads();
    }

    #pragma unroll
    for (int i = 0; i < 8; i++) {
        int cp = ct + (i < 4 ? ty * 4 + i : 64 + ty * 4 + (i - 4));
        int creal = (cp >> 3) * 24 + (cp & 7);
        float s = scale[creal];
        float bi = bias[creal];
        float4 v0, v1;
        v0.x = fmaxf(acc[i][0] * s + bi, 0.f);
        v0.y = fmaxf(acc[i][1] * s + bi, 0.f);
        v0.z = fmaxf(acc[i][2] * s + bi, 0.f);
        v0.w = fmaxf(acc[i][3] * s + bi, 0.f);
        v1.x = fmaxf(acc[i][4] * s + bi, 0.f);
        v1.y = fmaxf(acc[i][5] * s + bi, 0.f);
        v1.z = fmaxf(acc[i][6] * s + bi, 0.f);
        v1.w = fmaxf(acc[i][7] * s + bi, 0.f);
        float* dst = Qf + ((size_t)b * 256 + cp) * HW + pt;
        *reinterpret_cast<float4*>(dst + tx * 4)      = v0;
        *reinterpret_cast<float4*>(dst + 64 + tx * 4) = v1;
    }
}

// ---------------------------------------------------------------------------
// K1b: k/v channels (packed 512) via bf16 hi/lo 3-pass MFMA (~f32 accurate).
// Packed c' in [0,512): real = (c'>>4)*24 + 8 + (c'&15). Out f32.
// ---------------------------------------------------------------------------
__global__ __launch_bounds__(256) void conv_kv_mfma(
    const float* __restrict__ x,
    const float* __restrict__ w,
    const float* __restrict__ scale,
    const float* __restrict__ bias,
    float* __restrict__ KV)           // (B, 512, HW) packed k/v, f32
{
    const int ct = blockIdx.x, pt = blockIdx.y, b = blockIdx.z;
    const int tid  = threadIdx.x;
    const int wv   = tid >> 6, lane = tid & 63;
    const int u    = lane & 15, q8 = (lane >> 4) * 8;
    const int chb  = ct * 128 + (wv >> 1) * 64;
    const int pxb  = pt * 128 + (wv & 1) * 64;

    floatx4 acc[4][4];
    #pragma unroll
    for (int i = 0; i < 4; i++)
        #pragma unroll
        for (int j = 0; j < 4; j++) acc[i][j] = (floatx4)0.f;

    for (int kc = 0; kc < 8; kc++) {
        const int k0 = kc * 32 + q8;
        short8 ahi[4], alo[4];
        #pragma unroll
        for (int mt = 0; mt < 4; mt++) {
            int cp = chb + mt * 16 + u;
            int creal = (cp >> 4) * 24 + 8 + (cp & 15);
            const float* wp = w + (size_t)creal * CIN + k0;
            #pragma unroll
            for (int j = 0; j < 8; j++) {
                float f = wp[j];
                short h = f32_to_bf16(f);
                ahi[mt][j] = h;
                alo[mt][j] = f32_to_bf16(f - bf16_to_f32(h));
            }
        }
        short8 bhi[4], blo[4];
        #pragma unroll
        for (int nt = 0; nt < 4; nt++) {
            const float* xp = x + ((size_t)b * CIN + k0) * HW + pxb + nt * 16 + u;
            #pragma unroll
            for (int j = 0; j < 8; j++) {
                float f = xp[(size_t)j * HW];
                short h = f32_to_bf16(f);
                bhi[nt][j] = h;
                blo[nt][j] = f32_to_bf16(f - bf16_to_f32(h));
            }
        }
        #pragma unroll
        for (int mt = 0; mt < 4; mt++)
            #pragma unroll
            for (int nt = 0; nt < 4; nt++) {
                acc[mt][nt] = __builtin_amdgcn_mfma_f32_16x16x32_bf16(ahi[mt], bhi[nt], acc[mt][nt], 0, 0, 0);
                acc[mt][nt] = __builtin_amdgcn_mfma_f32_16x16x32_bf16(ahi[mt], blo[nt], acc[mt][nt], 0, 0, 0);
                acc[mt][nt] = __builtin_amdgcn_mfma_f32_16x16x32_bf16(alo[mt], bhi[nt], acc[mt][nt], 0, 0, 0);
            }
    }

    const int quad = lane >> 4;
    #pragma unroll
    for (int mt = 0; mt < 4; mt++)
        #pragma unroll
        for (int r = 0; r < 4; r++) {
            int cp = chb + mt * 16 + quad * 4 + r;
            int creal = (cp >> 4) * 24 + 8 + (cp & 15);
            float s = scale[creal], bi = bias[creal];
            #pragma unroll
            for (int nt = 0; nt < 4; nt++) {
                int px = pxb + nt * 16 + u;
                KV[((size_t)b * 512 + cp) * HW + px] = fmaxf(acc[mt][nt][r] * s + bi, 0.f);
            }
        }
}

// ---------------------------------------------------------------------------
// K0z: zero the stats region (atomic consumers below; re-entrant per launch).
// ---------------------------------------------------------------------------
__global__ __launch_bounds__(256) void zero_stats(float* __restrict__ stats)
{
    int i = blockIdx.x * 256 + threadIdx.x;
    if (i < BATCH * 64 * 72) stats[i] = 0.f;
}

// ---------------------------------------------------------------------------
// K2 v6: stats heads 0..31 via MFMA GRAM. Lane (c=lane&15, kg=lane>>4)
// streams 8 px of channel c per 32-px step; same short8 is both A-row c and
// B-col c of mfma_f32_16x16x32_bf16 -> D = Gram (16x16); rows 8..15 x cols
// 0..7 = vk. ksum via B=ones MFMA. bf16 hi/lo 3-pass ~f32. No acc[72], no
// shuffle reduce, no LDS, no barriers; ~72 atomics/wave.
// grid (32 h, 4 ps, 16 b) = 2048 blocks.
// ---------------------------------------------------------------------------
__global__ __launch_bounds__(256) void attn_stats_direct(
    const float* __restrict__ KV,
    float* __restrict__ stats)
{
    const int h = blockIdx.x, ps = blockIdx.y, b = blockIdx.z;
    const int tid = threadIdx.x;
    const int lane = tid & 63, wv = tid >> 6;
    const int c  = lane & 15;
    const int kg = lane >> 4;

    const float* cb = KV + ((size_t)b * 512 + h * 16 + c) * HW
                    + ps * 1024 + wv * 256 + kg * 8;

    floatx4 accg = (floatx4)0.f;     // gram
    floatx4 accs = (floatx4)0.f;     // rowsums (ksum in rows 0..7)
    short8 ones;
    #pragma unroll
    for (int j = 0; j < 8; j++) ones[j] = (short)0x3F80;  // bf16 1.0

    for (int st = 0; st < 8; st++) {
        float4 f0 = *reinterpret_cast<const float4*>(cb + st * 32);
        float4 f1 = *reinterpret_cast<const float4*>(cb + st * 32 + 4);
        float v[8] = {f0.x, f0.y, f0.z, f0.w, f1.x, f1.y, f1.z, f1.w};
        short8 hi, lo;
        #pragma unroll
        for (int j = 0; j < 8; j++) {
            short hh = f32_to_bf16(v[j]);
            hi[j] = hh;
            lo[j] = f32_to_bf16(v[j] - bf16_to_f32(hh));
        }
        accg = __builtin_amdgcn_mfma_f32_16x16x32_bf16(hi, hi, accg, 0, 0, 0);
        accg = __builtin_amdgcn_mfma_f32_16x16x32_bf16(hi, lo, accg, 0, 0, 0);
        accg = __builtin_amdgcn_mfma_f32_16x16x32_bf16(lo, hi, accg, 0, 0, 0);
        accs = __builtin_amdgcn_mfma_f32_16x16x32_bf16(hi, ones, accs, 0, 0, 0);
        accs = __builtin_amdgcn_mfma_f32_16x16x32_bf16(lo, ones, accs, 0, 0, 0);
    }

    // D layout: col = lane&15, row = (lane>>4)*4 + r
    float* sb = stats + ((size_t)b * 64 + h) * 72;
    if (c < 8 && kg >= 2) {           // rows 8..15 (v), cols 0..7 (k)
        #pragma unroll
        for (int r = 0; r < 4; r++)
            atomicAdd(sb + ((kg - 2) * 4 + r) * 8 + c, accg[r]);
    }
    if (c == 0 && kg < 2) {           // ksum rows 0..7, any col -> col 0
        #pragma unroll
        for (int r = 0; r < 4; r++)
            atomicAdd(sb + 64 + kg * 4 + r, accs[r]);
    }
}

// ---------------------------------------------------------------------------
// K3 v6: stats heads 32..63 = register 5x5 dwconv (f32) fused with MFMA GRAM.
// Lane (c, kg) convs 8 px of channel c per 32-px step (4 aligned float4 per
// row, wave-uniform row-validity branch, x-edges via 2 clamped offsets + 4
// mask mults). Conv out -> affine -> relu (k lanes only) -> bf16 hi/lo ->
// gram/ksum MFMAs. acc = 8 AGPRs; no LDS, no barriers, no big reduce.
// grid (32 hp, 2 ysb, 16 b) = 1024 blocks; wave = 8 rows (16 steps).
// ---------------------------------------------------------------------------
__global__ __launch_bounds__(256) void attn_stats_dw(
    const float* __restrict__ KV,
    const float* __restrict__ dww, const float* __restrict__ dwb,
    const float* __restrict__ pww, const float* __restrict__ pwb,
    float* __restrict__ stats)
{
    const int hp = blockIdx.x, ysb = blockIdx.y, b = blockIdx.z;
    const int tid = threadIdx.x;
    const int lane = tid & 63, wv = tid >> 6;
    const int c  = lane & 15;
    const int kg = lane >> 4;
    const int creal = hp * 24 + 8 + c;

    float wt[25];
    #pragma unroll
    for (int i = 0; i < 25; i++) wt[i] = dww[creal * 25 + i];
    const float pw = pww[creal];
    const float pb = pw * dwb[creal] + pwb[creal];

    const float* cb = KV + ((size_t)b * 512 + hp * 16 + c) * HW;
    const int ybase = ysb * 32 + wv * 8;

    floatx4 accg = (floatx4)0.f;
    floatx4 accs = (floatx4)0.f;
    short8 ones;
    #pragma unroll
    for (int j = 0; j < 8; j++) ones[j] = (short)0x3F80;

    for (int yy = 0; yy < 8; yy++) {
        const int y = ybase + yy;
        #pragma unroll
        for (int xh = 0; xh < 2; xh++) {
            const int x0 = xh * 32 + kg * 8;
            const float mL = (x0 == 0)  ? 0.f : 1.f;
            const float mR = (x0 == 56) ? 0.f : 1.f;
            const int colL = (x0 == 0)  ? 0  : x0 - 4;
            const int colR = (x0 == 56) ? 56 : x0 + 8;
            float out[8] = {};
            #pragma unroll
            for (int rr = 0; rr < 5; rr++) {
                const int ry = y - 2 + rr;
                float4 Q0 = {0,0,0,0}, Q1 = {0,0,0,0}, Q2 = {0,0,0,0}, Q3 = {0,0,0,0};
                if (ry >= 0 && ry < WIMG) {      // wave-uniform
                    const float* rp = cb + ry * WIMG;
                    Q0 = *reinterpret_cast<const float4*>(rp + colL);
                    Q1 = *reinterpret_cast<const float4*>(rp + x0);
                    Q2 = *reinterpret_cast<const float4*>(rp + x0 + 4);
                    Q3 = *reinterpret_cast<const float4*>(rp + colR);
                }
                float win[12] = {Q0.z * mL, Q0.w * mL,
                                 Q1.x, Q1.y, Q1.z, Q1.w,
                                 Q2.x, Q2.y, Q2.z, Q2.w,
                                 Q3.x * mR, Q3.y * mR};
                #pragma unroll
                for (int kx = 0; kx < 5; kx++) {
                    float w5 = wt[rr * 5 + kx];
                    #pragma unroll
                    for (int j = 0; j < 8; j++)
                        out[j] += w5 * win[j + kx];
                }
            }
            short8 hi, lo;
            #pragma unroll
            for (int j = 0; j < 8; j++) {
                float v = out[j] * pw + pb;
                float vr = fmaxf(v, 0.f);
                v = (c < 8) ? vr : v;            // relu k-channels only
                short hh = f32_to_bf16(v);
                hi[j] = hh;
                lo[j] = f32_to_bf16(v - bf16_to_f32(hh));
            }
            accg = __builtin_amdgcn_mfma_f32_16x16x32_bf16(hi, hi, accg, 0, 0, 0);
            accg = __builtin_amdgcn_mfma_f32_16x16x32_bf16(hi, lo, accg, 0, 0, 0);
            accg = __builtin_amdgcn_mfma_f32_16x16x32_bf16(lo, hi, accg, 0, 0, 0);
            accs = __builtin_amdgcn_mfma_f32_16x16x32_bf16(hi, ones, accs, 0, 0, 0);
            accs = __builtin_amdgcn_mfma_f32_16x16x32_bf16(lo, ones, accs, 0, 0, 0);
        }
    }

    float* sb = stats + ((size_t)b * 64 + 32 + hp) * 72;
    if (c < 8 && kg >= 2) {
        #pragma unroll
        for (int r = 0; r < 4; r++)
            atomicAdd(sb + ((kg - 2) * 4 + r) * 8 + c, accg[r]);
    }
    if (c == 0 && kg < 2) {
        #pragma unroll
        for (int r = 0; r < 4; r++)
            atomicAdd(sb + 64 + kg * 4 + r, accs[r]);
    }
}

// ---------------------------------------------------------------------------
// K3b v6: Qagg = register 5x5 dwconv + affine of q channels; same per-lane
// conv as K3 v6, no stats. Lane (c=lane&7, g=lane>>3) does 8 px of channel c;
// one wave covers a full 64-px row x 8 channels per step. Raw out (relu K5).
// grid (32 hb, 2 ysb, 16 b) = 1024 blocks; disjoint float4 stores.
// ---------------------------------------------------------------------------
__global__ __launch_bounds__(256) void q_dwconv(
    const float* __restrict__ Qf,     // (B,256,HW) packed q
    const float* __restrict__ dww, const float* __restrict__ dwb,
    const float* __restrict__ pww, const float* __restrict__ pwb,
    float* __restrict__ Qagg)         // (B,256,HW) packed dwconv(q)
{
    const int hb = blockIdx.x, ysb = blockIdx.y, b = blockIdx.z;
    const int tid = threadIdx.x;
    const int lane = tid & 63, wv = tid >> 6;
    const int c = lane & 7;
    const int g = lane >> 3;          // 0..7
    const int x0 = g * 8;
    const int creal = hb * 24 + c;

    float wt[25];
    #pragma unroll
    for (int i = 0; i < 25; i++) wt[i] = dww[creal * 25 + i];
    const float pw = pww[creal];
    const float pb = pw * dwb[creal] + pwb[creal];

    const float mL = (x0 == 0)  ? 0.f : 1.f;
    const float mR = (x0 == 56) ? 0.f : 1.f;
    const int colL = (x0 == 0)  ? 0  : x0 - 4;
    const int colR = (x0 == 56) ? 56 : x0 + 8;

    const float* cbase = Qf   + ((size_t)b * 256 + hb * 8 + c) * HW;
    float*       obase = Qagg + ((size_t)b * 256 + hb * 8 + c) * HW;
    const int ybase = ysb * 32 + wv * 8;

    for (int yy = 0; yy < 8; yy++) {
        const int y = ybase + yy;
        float out[8] = {};
        #pragma unroll
        for (int rr = 0; rr < 5; rr++) {
            const int ry = y - 2 + rr;
            float4 Q0 = {0,0,0,0}, Q1 = {0,0,0,0}, Q2 = {0,0,0,0}, Q3 = {0,0,0,0};
            if (ry >= 0 && ry < WIMG) {
                const float* rp = cbase + ry * WIMG;
                Q0 = *reinterpret_cast<const float4*>(rp + colL);
                Q1 = *reinterpret_cast<const float4*>(rp + x0);
                Q2 = *reinterpret_cast<const float4*>(rp + x0 + 4);
                Q3 = *reinterpret_cast<const float4*>(rp + colR);
            }
            float win[12] = {Q0.z * mL, Q0.w * mL,
                             Q1.x, Q1.y, Q1.z, Q1.w,
                             Q2.x, Q2.y, Q2.z, Q2.w,
                             Q3.x * mR, Q3.y * mR};
            #pragma unroll
            for (int kx = 0; kx < 5; kx++) {
                float w5 = wt[rr * 5 + kx];
                #pragma unroll
                for (int j = 0; j < 8; j++)
                    out[j] += w5 * win[j + kx];
            }
        }
        float4 o0 = {out[0] * pw + pb, out[1] * pw + pb,
                     out[2] * pw + pb, out[3] * pw + pb};
        float4 o1 = {out[4] * pw + pb, out[5] * pw + pb,
                     out[6] * pw + pb, out[7] * pw + pb};
        float* dst = obase + y * WIMG + x0;
        *reinterpret_cast<float4*>(dst)     = o0;
        *reinterpret_cast<float4*>(dst + 4) = o1;
    }
}

// ---------------------------------------------------------------------------
// K4: fold proj weights with vk, COLUMN-RESCALED by g_e = ksum_e + eps:
// M'[b][c][h*8+e] = (sum_d w[c][h*8+d]*vk[h][d][e]) / g_{h,e}. f16 hi/lo.
// ---------------------------------------------------------------------------
__global__ __launch_bounds__(256) void build_M(
    const float* __restrict__ stats,   // (B,64,72)
    const float* __restrict__ projw,   // (256,512)
    _Float16* __restrict__ Mhi,        // (B,256,512)
    _Float16* __restrict__ Mlo)
{
    const int b = blockIdx.x;
    const int tid = threadIdx.x;
    __shared__ float svk[64][64];
    __shared__ float sginv[64][8];
    for (int i = tid; i < 64 * 64; i += 256)
        svk[i >> 6][i & 63] = stats[((size_t)b * 64 + (i >> 6)) * 72 + (i & 63)];
    for (int i = tid; i < 512; i += 256)
        sginv[i >> 3][i & 7] =
            1.0f / (stats[((size_t)b * 64 + (i >> 3)) * 72 + 64 + (i & 7)] + EPS_F);
    __syncthreads();

    const float* wr = projw + (size_t)tid * 512;
    for (int h = 0; h < 64; h++) {
        float wv[8];
        float4 a0 = *reinterpret_cast<const float4*>(wr + h * 8);
        float4 a1 = *reinterpret_cast<const float4*>(wr + h * 8 + 4);
        wv[0]=a0.x; wv[1]=a0.y; wv[2]=a0.z; wv[3]=a0.w;
        wv[4]=a1.x; wv[5]=a1.y; wv[6]=a1.z; wv[7]=a1.w;
        union { _Float16 h8[8]; uint4 u; } hi, lo;
        #pragma unroll
        for (int e = 0; e < 8; e++) {
            float s = 0.f;
            #pragma unroll
            for (int d = 0; d < 8; d++) s += wv[d] * svk[h][d * 8 + e];
            s *= sginv[h][e];
            _Float16 sh = (_Float16)s;
            hi.h8[e] = sh;
            lo.h8[e] = (_Float16)(s - (float)sh);
        }
        *reinterpret_cast<uint4*>(Mhi + ((size_t)b * 256 + tid) * 512 + h * 8) = hi.u;
        *reinterpret_cast<uint4*>(Mlo + ((size_t)b * 256 + tid) * 512 + h * 8) = lo.u;
    }
}

// ---------------------------------------------------------------------------
// K5: 128-px tile, 4 barriers total. Qt_e = QSCALE*g_e*q_e/den (bounded),
// f16; two half-K phases (heads 0..31 from Qf, 32..63 from Qagg), each a
// 2-pass hi/lo f16 MFMA GEMM (256ch x 128px). LDS ~70 KB -> 2 blocks/CU.
// ---------------------------------------------------------------------------
__global__ __launch_bounds__(256) void attn_proj_mfma(
    const float* __restrict__ Qf,      // (B,256,HW) packed q (>=0)
    const float* __restrict__ Qagg,    // (B,256,HW) packed dwconv(q), raw
    const float* __restrict__ stats,   // ksum at [64..71]
    const _Float16* __restrict__ Mhi,  // (B,256,512)
    const _Float16* __restrict__ Mlo,
    const float* __restrict__ scale, const float* __restrict__ bias,
    float* __restrict__ out)           // (B,256,HW)
{
    const int pt  = blockIdx.x * 128;
    const int b   = blockIdx.y;
    const int tid = threadIdx.x;
    const int wv  = tid >> 6, lane = tid & 63;

    __shared__ _Float16 Qt[128][264];     // 67.6 KB half-K [px][k]
    __shared__ float    ksums[64][8];     // 2 KB

    for (int i = tid; i < 512; i += 256)
        ksums[i >> 3][i & 7] = stats[((size_t)b * 64 + (i >> 3)) * 72 + 64 + (i & 7)];
    __syncthreads();

    const int pxl = tid & 127;            // local pixel for Qt build
    const int eg  = (tid >> 7) * 4;       // 4 e's per thread
    const int u = lane & 15, q8 = (lane >> 4) * 8;
    const int quad = lane >> 4;

    floatx4 acc[4][8];
    #pragma unroll
    for (int i = 0; i < 4; i++)
        #pragma unroll
        for (int j = 0; j < 8; j++) acc[i][j] = (floatx4)0.f;

    // ============ phase A: heads 0..31 (q direct from Qf, >=0) ============
    for (int h = 0; h < 32; h++) {
        const float* qp = Qf + ((size_t)b * 256 + h * 8) * HW + pt + pxl;
        float qv[8];
        #pragma unroll
        for (int e = 0; e < 8; e++) qv[e] = qp[(size_t)e * HW];
        float den = EPS_F;
        #pragma unroll
        for (int e = 0; e < 8; e++) den += ksums[h][e] * qv[e];
        float rd = QSCALE / den;
        union { _Float16 h4[4]; uint2 u2; } pk;
        #pragma unroll
        for (int j = 0; j < 4; j++) {
            float g = ksums[h][eg + j] + EPS_F;
            pk.h4[j] = (_Float16)fminf(qv[eg + j] * g * rd, 60000.f);
        }
        *reinterpret_cast<uint2*>(&Qt[pxl][h * 8 + eg]) = pk.u2;
    }
    __syncthreads();

    for (int ks = 0; ks < 8; ks++) {
        half8 ah[4], al[4], bf[8];
        #pragma unroll
        for (int mt = 0; mt < 4; mt++) {
            size_t moff = ((size_t)b * 256 + wv * 64 + mt * 16 + u) * 512 + ks * 32 + q8;
            ah[mt] = *reinterpret_cast<const half8*>(Mhi + moff);
            al[mt] = *reinterpret_cast<const half8*>(Mlo + moff);
        }
        #pragma unroll
        for (int nt = 0; nt < 8; nt++)
            bf[nt] = *reinterpret_cast<const half8*>(&Qt[nt * 16 + u][ks * 32 + q8]);
        #pragma unroll
        for (int mt = 0; mt < 4; mt++)
            #pragma unroll
            for (int nt = 0; nt < 8; nt++) {
                acc[mt][nt] = __builtin_amdgcn_mfma_f32_16x16x32_f16(ah[mt], bf[nt], acc[mt][nt], 0, 0, 0);
                acc[mt][nt] = __builtin_amdgcn_mfma_f32_16x16x32_f16(al[mt], bf[nt], acc[mt][nt], 0, 0, 0);
            }
    }
    __syncthreads();

    // ============ phase B: heads 32..63 (q from Qagg, needs relu) ==========
    for (int h = 32; h < 64; h++) {
        const int hb = h - 32;
        const float* qp = Qagg + ((size_t)b * 256 + hb * 8) * HW + pt + pxl;
        float qv[8];
        #pragma unroll
        for (int e = 0; e < 8; e++) qv[e] = fmaxf(qp[(size_t)e * HW], 0.f);
        float den = EPS_F;
        #pragma unroll
        for (int e = 0; e < 8; e++) den += ksums[h][e] * qv[e];
        float rd = QSCALE / den;
        union { _Float16 h4[4]; uint2 u2; } pk;
        #pragma unroll
        for (int j = 0; j < 4; j++) {
            float g = ksums[h][eg + j] + EPS_F;
            pk.h4[j] = (_Float16)fminf(qv[eg + j] * g * rd, 60000.f);
        }
        *reinterpret_cast<uint2*>(&Qt[pxl][hb * 8 + eg]) = pk.u2;
    }
    __syncthreads();

    for (int ks = 0; ks < 8; ks++) {
        half8 ah[4], al[4], bf[8];
        #pragma unroll
        for (int mt = 0; mt < 4; mt++) {
            size_t moff = ((size_t)b * 256 + wv * 64 + mt * 16 + u) * 512 + 256 + ks * 32 + q8;
            ah[mt] = *reinterpret_cast<const half8*>(Mhi + moff);
            al[mt] = *reinterpret_cast<const half8*>(Mlo + moff);
        }
        #pragma unroll
        for (int nt = 0; nt < 8; nt++)
            bf[nt] = *reinterpret_cast<const half8*>(&Qt[nt * 16 + u][ks * 32 + q8]);
        #pragma unroll
        for (int mt = 0; mt < 4; mt++)
            #pragma unroll
            for (int nt = 0; nt < 8; nt++) {
                acc[mt][nt] = __builtin_amdgcn_mfma_f32_16x16x32_f16(ah[mt], bf[nt], acc[mt][nt], 0, 0, 0);
                acc[mt][nt] = __builtin_amdgcn_mfma_f32_16x16x32_f16(al[mt], bf[nt], acc[mt][nt], 0, 0, 0);
            }
    }

    #pragma unroll
    for (int mt = 0; mt < 4; mt++)
        #pragma unroll
        for (int r = 0; r < 4; r++) {
            int c = wv * 64 + mt * 16 + quad * 4 + r;
            float s = scale[c] * (1.0f / QSCALE);
            float bi = bias[c];
            #pragma unroll
            for (int nt = 0; nt < 8; nt++) {
                int px = pt + nt * 16 + u;
                out[((size_t)b * COUT + c) * HW + px] = fmaxf(acc[mt][nt][r] * s + bi, 0.f);
            }
        }
}

// ---------------------------------------------------------------------------
extern "C" void kernel_launch(void* const* d_in, const int* in_sizes, int n_in,
                              void* d_out, int out_size, void* d_ws, size_t ws_size,
                              hipStream_t stream)
{
    const float* x      = (const float*)d_in[0];
    const float* qkv_w  = (const float*)d_in[1];
    const float* qkv_s  = (const float*)d_in[2];
    const float* qkv_b  = (const float*)d_in[3];
    const float* dw_w   = (const float*)d_in[4];
    const float* dw_b   = (const float*)d_in[5];
    const float* pw_w   = (const float*)d_in[6];
    const float* pw_b   = (const float*)d_in[7];
    const float* proj_w = (const float*)d_in[8];
    const float* proj_s = (const float*)d_in[9];
    const float* proj_b = (const float*)d_in[10];
    float* out = (float*)d_out;

    // ws layout (exactly the PROVEN 192.3 MiB):
    //   [0,128 MiB)    KV f32 — dead after K2/K3; reused: Mhi(4)+Mlo(4)+Qagg(64)
    //   [128,192 MiB)  Qf f32
    //   [192 MiB,+288K) stats
    float*    KV    = (float*)d_ws;
    _Float16* Mhi   = (_Float16*)d_ws;                          // +0
    _Float16* Mlo   = Mhi + (size_t)BATCH * 256 * 512;          // +4 MiB
    float*    Qagg  = (float*)(Mlo + (size_t)BATCH * 256 * 512);// +8 MiB (64 MiB)
    float*    Qf    = KV + (size_t)BATCH * 512 * HW;            // +128 MiB
    float*    stats = Qf + (size_t)BATCH * 256 * HW;            // +192 MiB

    conv_q_f32<<<dim3(HW / 128, 2, BATCH), 256, 0, stream>>>(
        x, qkv_w, qkv_s, qkv_b, Qf);

    conv_kv_mfma<<<dim3(4, 32, BATCH), 256, 0, stream>>>(
        x, qkv_w, qkv_s, qkv_b, KV);

    // zero stats before the atomic-reduce stats kernels
    zero_stats<<<dim3((BATCH * 64 * 72 + 255) / 256), 256, 0, stream>>>(stats);

    attn_stats_direct<<<dim3(32, 4, BATCH), 256, 0, stream>>>(KV, stats);

    attn_stats_dw<<<dim3(32, 2, BATCH), 256, 0, stream>>>(
        KV, dw_w, dw_b, pw_w, pw_b, stats);

    // after K2/K3: KV region dead -> safe to overwrite with Qagg / M
    q_dwconv<<<dim3(32, 2, BATCH), 256, 0, stream>>>(
        Qf, dw_w, dw_b, pw_w, pw_b, Qagg);

    build_M<<<dim3(BATCH), 256, 0, stream>>>(stats, proj_w, Mhi, Mlo);

    attn_proj_mfma<<<dim3(HW / 128, BATCH), 256, 0, stream>>>(
        Qf, Qagg, stats, Mhi, Mlo, proj_s, proj_b, out);
}

// Round 7
// 720.580 us; speedup vs baseline: 1.3347x; 1.2412x over previous
//
#include <hip/hip_runtime.h>

#define HW    4096
#define WIMG  64
#define CIN   256
#define C3    768
#define COUT  256
#define BATCH 16
#define NHB   32
#define EPS_F 1e-5f
#define QSCALE 1024.0f   // pow2: exactly undone in epilogue

typedef __attribute__((ext_vector_type(8))) short    short8;
typedef __attribute__((ext_vector_type(8))) _Float16 half8;
typedef __attribute__((ext_vector_type(4))) float    floatx4;

__device__ inline short f32_to_bf16(float f) {
    unsigned u = __builtin_bit_cast(unsigned, f);
    unsigned r = u + 0x7fffu + ((u >> 16) & 1u);
    return (short)(r >> 16);
}
__device__ inline float bf16_to_f32(short s) {
    return __builtin_bit_cast(float, ((unsigned)(unsigned short)s) << 16);
}

// ---------------------------------------------------------------------------
// K1a: q channels (packed 256) of qkv 1x1 conv, f32 VALU GEMM.
// 128x128 tile, 8x8 per thread (split as {t*4, 64+t*4} for 2-way-free LDS).
// q needs f32 absolute accuracy (eps-denominator cliff).
// Packed c' in [0,256): real C3 channel = (c'>>3)*24 + (c'&7).
// ---------------------------------------------------------------------------
__global__ __launch_bounds__(256) void conv_q_f32(
    const float* __restrict__ in,     // (B, 256, HW)
    const float* __restrict__ w,      // (768, 256)
    const float* __restrict__ scale,
    const float* __restrict__ bias,
    float* __restrict__ Qf)           // (B, 256, HW) packed q
{
    const int pt  = blockIdx.x * 128;
    const int ct  = blockIdx.y * 128;
    const int b   = blockIdx.z;
    const int tid = threadIdx.x;
    const int tx  = tid & 15;         // px groups tx*4 and 64+tx*4
    const int ty  = tid >> 4;         // ch groups ty*4 and 64+ty*4

    __shared__ float Ws[16][128];
    __shared__ float Xs[16][128];

    float acc[8][8] = {};
    const float* xb = in + (size_t)b * CIN * HW + pt;

    for (int k0 = 0; k0 < CIN; k0 += 16) {
        #pragma unroll
        for (int i = 0; i < 8; i++) {
            int idx = tid + i * 256;          // 0..2047
            int c = idx >> 4, k = idx & 15;
            int cp = ct + c;
            int creal = (cp >> 3) * 24 + (cp & 7);
            Ws[k][c] = w[(size_t)creal * CIN + k0 + k];
        }
        #pragma unroll
        for (int i = 0; i < 8; i++) {
            int idx = tid + i * 256;
            int k = idx >> 7, p = idx & 127;
            Xs[k][p] = xb[(size_t)(k0 + k) * HW + p];
        }
        __syncthreads();
        #pragma unroll
        for (int kk = 0; kk < 16; kk++) {
            float4 a0 = *reinterpret_cast<const float4*>(&Ws[kk][ty * 4]);
            float4 a1 = *reinterpret_cast<const float4*>(&Ws[kk][64 + ty * 4]);
            float4 b0 = *reinterpret_cast<const float4*>(&Xs[kk][tx * 4]);
            float4 b1 = *reinterpret_cast<const float4*>(&Xs[kk][64 + tx * 4]);
            float a[8] = {a0.x, a0.y, a0.z, a0.w, a1.x, a1.y, a1.z, a1.w};
            float bb[8] = {b0.x, b0.y, b0.z, b0.w, b1.x, b1.y, b1.z, b1.w};
            #pragma unroll
            for (int i = 0; i < 8; i++)
                #pragma unroll
                for (int j = 0; j < 8; j++)
                    acc[i][j] += a[i] * bb[j];
        }
        __syncthreads();
    }

    #pragma unroll
    for (int i = 0; i < 8; i++) {
        int cp = ct + (i < 4 ? ty * 4 + i : 64 + ty * 4 + (i - 4));
        int creal = (cp >> 3) * 24 + (cp & 7);
        float s = scale[creal];
        float bi = bias[creal];
        float4 v0, v1;
        v0.x = fmaxf(acc[i][0] * s + bi, 0.f);
        v0.y = fmaxf(acc[i][1] * s + bi, 0.f);
        v0.z = fmaxf(acc[i][2] * s + bi, 0.f);
        v0.w = fmaxf(acc[i][3] * s + bi, 0.f);
        v1.x = fmaxf(acc[i][4] * s + bi, 0.f);
        v1.y = fmaxf(acc[i][5] * s + bi, 0.f);
        v1.z = fmaxf(acc[i][6] * s + bi, 0.f);
        v1.w = fmaxf(acc[i][7] * s + bi, 0.f);
        float* dst = Qf + ((size_t)b * 256 + cp) * HW + pt;
        *reinterpret_cast<float4*>(dst + tx * 4)      = v0;
        *reinterpret_cast<float4*>(dst + 64 + tx * 4) = v1;
    }
}

// ---------------------------------------------------------------------------
// K1b: k/v channels (packed 512) via bf16 hi/lo 3-pass MFMA (~f32 accurate).
// Packed c' in [0,512): real = (c'>>4)*24 + 8 + (c'&15). Out f32.
// ---------------------------------------------------------------------------
__global__ __launch_bounds__(256) void conv_kv_mfma(
    const float* __restrict__ x,
    const float* __restrict__ w,
    const float* __restrict__ scale,
    const float* __restrict__ bias,
    float* __restrict__ KV)           // (B, 512, HW) packed k/v, f32
{
    const int ct = blockIdx.x, pt = blockIdx.y, b = blockIdx.z;
    const int tid  = threadIdx.x;
    const int wv   = tid >> 6, lane = tid & 63;
    const int u    = lane & 15, q8 = (lane >> 4) * 8;
    const int chb  = ct * 128 + (wv >> 1) * 64;
    const int pxb  = pt * 128 + (wv & 1) * 64;

    floatx4 acc[4][4];
    #pragma unroll
    for (int i = 0; i < 4; i++)
        #pragma unroll
        for (int j = 0; j < 4; j++) acc[i][j] = (floatx4)0.f;

    for (int kc = 0; kc < 8; kc++) {
        const int k0 = kc * 32 + q8;
        short8 ahi[4], alo[4];
        #pragma unroll
        for (int mt = 0; mt < 4; mt++) {
            int cp = chb + mt * 16 + u;
            int creal = (cp >> 4) * 24 + 8 + (cp & 15);
            const float* wp = w + (size_t)creal * CIN + k0;
            #pragma unroll
            for (int j = 0; j < 8; j++) {
                float f = wp[j];
                short h = f32_to_bf16(f);
                ahi[mt][j] = h;
                alo[mt][j] = f32_to_bf16(f - bf16_to_f32(h));
            }
        }
        short8 bhi[4], blo[4];
        #pragma unroll
        for (int nt = 0; nt < 4; nt++) {
            const float* xp = x + ((size_t)b * CIN + k0) * HW + pxb + nt * 16 + u;
            #pragma unroll
            for (int j = 0; j < 8; j++) {
                float f = xp[(size_t)j * HW];
                short h = f32_to_bf16(f);
                bhi[nt][j] = h;
                blo[nt][j] = f32_to_bf16(f - bf16_to_f32(h));
            }
        }
        #pragma unroll
        for (int mt = 0; mt < 4; mt++)
            #pragma unroll
            for (int nt = 0; nt < 4; nt++) {
                acc[mt][nt] = __builtin_amdgcn_mfma_f32_16x16x32_bf16(ahi[mt], bhi[nt], acc[mt][nt], 0, 0, 0);
                acc[mt][nt] = __builtin_amdgcn_mfma_f32_16x16x32_bf16(ahi[mt], blo[nt], acc[mt][nt], 0, 0, 0);
                acc[mt][nt] = __builtin_amdgcn_mfma_f32_16x16x32_bf16(alo[mt], bhi[nt], acc[mt][nt], 0, 0, 0);
            }
    }

    const int quad = lane >> 4;
    #pragma unroll
    for (int mt = 0; mt < 4; mt++)
        #pragma unroll
        for (int r = 0; r < 4; r++) {
            int cp = chb + mt * 16 + quad * 4 + r;
            int creal = (cp >> 4) * 24 + 8 + (cp & 15);
            float s = scale[creal], bi = bias[creal];
            #pragma unroll
            for (int nt = 0; nt < 4; nt++) {
                int px = pxb + nt * 16 + u;
                KV[((size_t)b * 512 + cp) * HW + px] = fmaxf(acc[mt][nt][r] * s + bi, 0.f);
            }
        }
}

// ---------------------------------------------------------------------------
// K0z: zero the stats region (atomic consumers below; re-entrant per launch).
// ---------------------------------------------------------------------------
__global__ __launch_bounds__(256) void zero_stats(float* __restrict__ stats)
{
    int i = blockIdx.x * 256 + threadIdx.x;
    if (i < BATCH * 64 * 72) stats[i] = 0.f;
}

// ---------------------------------------------------------------------------
// K2 v6: stats heads 0..31 via MFMA GRAM. Lane (c=lane&15, kg=lane>>4)
// streams 8 px of channel c per 32-px step; same short8 is both A-row c and
// B-col c of mfma_f32_16x16x32_bf16 -> D = Gram (16x16); rows 8..15 x cols
// 0..7 = vk. ksum via B=ones MFMA. bf16 hi/lo 3-pass ~f32. No LDS/barriers.
// grid (32 h, 4 ps, 16 b) = 2048 blocks.
// ---------------------------------------------------------------------------
__global__ __launch_bounds__(256) void attn_stats_direct(
    const float* __restrict__ KV,
    float* __restrict__ stats)
{
    const int h = blockIdx.x, ps = blockIdx.y, b = blockIdx.z;
    const int tid = threadIdx.x;
    const int lane = tid & 63, wv = tid >> 6;
    const int c  = lane & 15;
    const int kg = lane >> 4;

    const float* cb = KV + ((size_t)b * 512 + h * 16 + c) * HW
                    + ps * 1024 + wv * 256 + kg * 8;

    floatx4 accg = (floatx4)0.f;     // gram
    floatx4 accs = (floatx4)0.f;     // rowsums (ksum in rows 0..7)
    short8 ones;
    #pragma unroll
    for (int j = 0; j < 8; j++) ones[j] = (short)0x3F80;  // bf16 1.0

    for (int st = 0; st < 8; st++) {
        float4 f0 = *reinterpret_cast<const float4*>(cb + st * 32);
        float4 f1 = *reinterpret_cast<const float4*>(cb + st * 32 + 4);
        float v[8] = {f0.x, f0.y, f0.z, f0.w, f1.x, f1.y, f1.z, f1.w};
        short8 hi, lo;
        #pragma unroll
        for (int j = 0; j < 8; j++) {
            short hh = f32_to_bf16(v[j]);
            hi[j] = hh;
            lo[j] = f32_to_bf16(v[j] - bf16_to_f32(hh));
        }
        accg = __builtin_amdgcn_mfma_f32_16x16x32_bf16(hi, hi, accg, 0, 0, 0);
        accg = __builtin_amdgcn_mfma_f32_16x16x32_bf16(hi, lo, accg, 0, 0, 0);
        accg = __builtin_amdgcn_mfma_f32_16x16x32_bf16(lo, hi, accg, 0, 0, 0);
        accs = __builtin_amdgcn_mfma_f32_16x16x32_bf16(hi, ones, accs, 0, 0, 0);
        accs = __builtin_amdgcn_mfma_f32_16x16x32_bf16(lo, ones, accs, 0, 0, 0);
    }

    // D layout: col = lane&15, row = (lane>>4)*4 + r
    float* sb = stats + ((size_t)b * 64 + h) * 72;
    if (c < 8 && kg >= 2) {           // rows 8..15 (v), cols 0..7 (k)
        #pragma unroll
        for (int r = 0; r < 4; r++)
            atomicAdd(sb + ((kg - 2) * 4 + r) * 8 + c, accg[r]);
    }
    if (c == 0 && kg < 2) {           // ksum rows 0..7, any col -> col 0
        #pragma unroll
        for (int r = 0; r < 4; r++)
            atomicAdd(sb + 64 + kg * 4 + r, accs[r]);
    }
}

// ---------------------------------------------------------------------------
// K3 v7: stats heads 32..63 = rolling-window 5x5 dwconv fused with MFMA GRAM.
// Each input row is loaded ONCE (12 rows/strip) and scattered into the <=5
// live output-row accumulators out[5][8] (rotating slots, full unroll ->
// compile-time indices). When input li lands, output li-4 completes ->
// affine -> relu(k) -> bf16 hi/lo -> 5 Gram/ksum MFMAs -> slot reset.
// Cuts loads 3.3x vs v6 (FETCH 363 -> ~170 MB). No LDS, no barriers.
// grid (32 hp, 2 ysb, 16 b) = 1024 blocks; wave = 8 output rows.
// ---------------------------------------------------------------------------
__global__ __launch_bounds__(256) void attn_stats_dw(
    const float* __restrict__ KV,
    const float* __restrict__ dww, const float* __restrict__ dwb,
    const float* __restrict__ pww, const float* __restrict__ pwb,
    float* __restrict__ stats)
{
    const int hp = blockIdx.x, ysb = blockIdx.y, b = blockIdx.z;
    const int tid = threadIdx.x;
    const int lane = tid & 63, wv = tid >> 6;
    const int c  = lane & 15;
    const int kg = lane >> 4;
    const int creal = hp * 24 + 8 + c;

    float wt[25];
    #pragma unroll
    for (int i = 0; i < 25; i++) wt[i] = dww[creal * 25 + i];
    const float pw = pww[creal];
    const float pb = pw * dwb[creal] + pwb[creal];

    const float* cb = KV + ((size_t)b * 512 + hp * 16 + c) * HW;
    const int ybase = ysb * 32 + wv * 8;

    floatx4 accg = (floatx4)0.f;
    floatx4 accs = (floatx4)0.f;
    short8 ones;
    #pragma unroll
    for (int j = 0; j < 8; j++) ones[j] = (short)0x3F80;

    #pragma unroll
    for (int xh = 0; xh < 2; xh++) {
        const int x0 = xh * 32 + kg * 8;
        const float mL = (x0 == 0)  ? 0.f : 1.f;
        const float mR = (x0 == 56) ? 0.f : 1.f;
        const int colL = (x0 == 0)  ? 0  : x0 - 4;
        const int colR = (x0 == 56) ? 56 : x0 + 8;

        float out[5][8] = {};
        #pragma unroll
        for (int li = 0; li < 12; li++) {
            const int ry = ybase + li - 2;
            float4 Q0 = {0,0,0,0}, Q1 = {0,0,0,0}, Q2 = {0,0,0,0}, Q3 = {0,0,0,0};
            if (ry >= 0 && ry < WIMG) {          // wave-uniform
                const float* rp = cb + ry * WIMG;
                Q0 = *reinterpret_cast<const float4*>(rp + colL);
                Q1 = *reinterpret_cast<const float4*>(rp + x0);
                Q2 = *reinterpret_cast<const float4*>(rp + x0 + 4);
                Q3 = *reinterpret_cast<const float4*>(rp + colR);
            }
            float win[12] = {Q0.z * mL, Q0.w * mL,
                             Q1.x, Q1.y, Q1.z, Q1.w,
                             Q2.x, Q2.y, Q2.z, Q2.w,
                             Q3.x * mR, Q3.y * mR};
            // scatter into live output rows lo = li-4..li
            #pragma unroll
            for (int rr = 0; rr < 5; rr++) {
                const int lo = li - rr;
                if (lo >= 0 && lo < 8) {
                    #pragma unroll
                    for (int kx = 0; kx < 5; kx++) {
                        float w5 = wt[rr * 5 + kx];
                        #pragma unroll
                        for (int j = 0; j < 8; j++)
                            out[lo % 5][j] += w5 * win[j + kx];
                    }
                }
            }
            // finalize completed output row lo = li-4
            const int lod = li - 4;
            if (lod >= 0 && lod < 8) {
                short8 hib, lob;
                #pragma unroll
                for (int j = 0; j < 8; j++) {
                    float v = out[lod % 5][j] * pw + pb;
                    float vr = fmaxf(v, 0.f);
                    v = (c < 8) ? vr : v;        // relu k-channels only
                    short hh = f32_to_bf16(v);
                    hib[j] = hh;
                    lob[j] = f32_to_bf16(v - bf16_to_f32(hh));
                }
                accg = __builtin_amdgcn_mfma_f32_16x16x32_bf16(hib, hib, accg, 0, 0, 0);
                accg = __builtin_amdgcn_mfma_f32_16x16x32_bf16(hib, lob, accg, 0, 0, 0);
                accg = __builtin_amdgcn_mfma_f32_16x16x32_bf16(lob, hib, accg, 0, 0, 0);
                accs = __builtin_amdgcn_mfma_f32_16x16x32_bf16(hib, ones, accs, 0, 0, 0);
                accs = __builtin_amdgcn_mfma_f32_16x16x32_bf16(lob, ones, accs, 0, 0, 0);
                #pragma unroll
                for (int j = 0; j < 8; j++) out[lod % 5][j] = 0.f;
            }
        }
    }

    float* sb = stats + ((size_t)b * 64 + 32 + hp) * 72;
    if (c < 8 && kg >= 2) {
        #pragma unroll
        for (int r = 0; r < 4; r++)
            atomicAdd(sb + ((kg - 2) * 4 + r) * 8 + c, accg[r]);
    }
    if (c == 0 && kg < 2) {
        #pragma unroll
        for (int r = 0; r < 4; r++)
            atomicAdd(sb + 64 + kg * 4 + r, accs[r]);
    }
}

// ---------------------------------------------------------------------------
// K3b v7: Qagg = rolling-window 5x5 dwconv + affine of q channels; each input
// row loaded once, out[5][8] rotating slots, finalize -> 2x float4 store.
// Lane (c=lane&7, g=lane>>3) covers 8 px of channel c; wave = full 64-px row
// x 8 channels. grid (32 hb, 2 ysb, 16 b) = 1024 blocks. Raw out (relu K5).
// ---------------------------------------------------------------------------
__global__ __launch_bounds__(256) void q_dwconv(
    const float* __restrict__ Qf,     // (B,256,HW) packed q
    const float* __restrict__ dww, const float* __restrict__ dwb,
    const float* __restrict__ pww, const float* __restrict__ pwb,
    float* __restrict__ Qagg)         // (B,256,HW) packed dwconv(q)
{
    const int hb = blockIdx.x, ysb = blockIdx.y, b = blockIdx.z;
    const int tid = threadIdx.x;
    const int lane = tid & 63, wv = tid >> 6;
    const int c = lane & 7;
    const int g = lane >> 3;          // 0..7
    const int x0 = g * 8;
    const int creal = hb * 24 + c;

    float wt[25];
    #pragma unroll
    for (int i = 0; i < 25; i++) wt[i] = dww[creal * 25 + i];
    const float pw = pww[creal];
    const float pb = pw * dwb[creal] + pwb[creal];

    const float mL = (x0 == 0)  ? 0.f : 1.f;
    const float mR = (x0 == 56) ? 0.f : 1.f;
    const int colL = (x0 == 0)  ? 0  : x0 - 4;
    const int colR = (x0 == 56) ? 56 : x0 + 8;

    const float* cbase = Qf   + ((size_t)b * 256 + hb * 8 + c) * HW;
    float*       obase = Qagg + ((size_t)b * 256 + hb * 8 + c) * HW;
    const int ybase = ysb * 32 + wv * 8;

    float out[5][8] = {};
    #pragma unroll
    for (int li = 0; li < 12; li++) {
        const int ry = ybase + li - 2;
        float4 Q0 = {0,0,0,0}, Q1 = {0,0,0,0}, Q2 = {0,0,0,0}, Q3 = {0,0,0,0};
        if (ry >= 0 && ry < WIMG) {
            const float* rp = cbase + ry * WIMG;
            Q0 = *reinterpret_cast<const float4*>(rp + colL);
            Q1 = *reinterpret_cast<const float4*>(rp + x0);
            Q2 = *reinterpret_cast<const float4*>(rp + x0 + 4);
            Q3 = *reinterpret_cast<const float4*>(rp + colR);
        }
        float win[12] = {Q0.z * mL, Q0.w * mL,
                         Q1.x, Q1.y, Q1.z, Q1.w,
                         Q2.x, Q2.y, Q2.z, Q2.w,
                         Q3.x * mR, Q3.y * mR};
        #pragma unroll
        for (int rr = 0; rr < 5; rr++) {
            const int lo = li - rr;
            if (lo >= 0 && lo < 8) {
                #pragma unroll
                for (int kx = 0; kx < 5; kx++) {
                    float w5 = wt[rr * 5 + kx];
                    #pragma unroll
                    for (int j = 0; j < 8; j++)
                        out[lo % 5][j] += w5 * win[j + kx];
                }
            }
        }
        const int lod = li - 4;
        if (lod >= 0 && lod < 8) {
            float4 o0 = {out[lod % 5][0] * pw + pb, out[lod % 5][1] * pw + pb,
                         out[lod % 5][2] * pw + pb, out[lod % 5][3] * pw + pb};
            float4 o1 = {out[lod % 5][4] * pw + pb, out[lod % 5][5] * pw + pb,
                         out[lod % 5][6] * pw + pb, out[lod % 5][7] * pw + pb};
            float* dst = obase + (ybase + lod) * WIMG + x0;
            *reinterpret_cast<float4*>(dst)     = o0;
            *reinterpret_cast<float4*>(dst + 4) = o1;
            #pragma unroll
            for (int j = 0; j < 8; j++) out[lod % 5][j] = 0.f;
        }
    }
}

// ---------------------------------------------------------------------------
// K4: fold proj weights with vk, COLUMN-RESCALED by g_e = ksum_e + eps:
// M'[b][c][h*8+e] = (sum_d w[c][h*8+d]*vk[h][d][e]) / g_{h,e}. f16 hi/lo.
// ---------------------------------------------------------------------------
__global__ __launch_bounds__(256) void build_M(
    const float* __restrict__ stats,   // (B,64,72)
    const float* __restrict__ projw,   // (256,512)
    _Float16* __restrict__ Mhi,        // (B,256,512)
    _Float16* __restrict__ Mlo)
{
    const int b = blockIdx.x;
    const int tid = threadIdx.x;
    __shared__ float svk[64][64];
    __shared__ float sginv[64][8];
    for (int i = tid; i < 64 * 64; i += 256)
        svk[i >> 6][i & 63] = stats[((size_t)b * 64 + (i >> 6)) * 72 + (i & 63)];
    for (int i = tid; i < 512; i += 256)
        sginv[i >> 3][i & 7] =
            1.0f / (stats[((size_t)b * 64 + (i >> 3)) * 72 + 64 + (i & 7)] + EPS_F);
    __syncthreads();

    const float* wr = projw + (size_t)tid * 512;
    for (int h = 0; h < 64; h++) {
        float wv[8];
        float4 a0 = *reinterpret_cast<const float4*>(wr + h * 8);
        float4 a1 = *reinterpret_cast<const float4*>(wr + h * 8 + 4);
        wv[0]=a0.x; wv[1]=a0.y; wv[2]=a0.z; wv[3]=a0.w;
        wv[4]=a1.x; wv[5]=a1.y; wv[6]=a1.z; wv[7]=a1.w;
        union { _Float16 h8[8]; uint4 u; } hi, lo;
        #pragma unroll
        for (int e = 0; e < 8; e++) {
            float s = 0.f;
            #pragma unroll
            for (int d = 0; d < 8; d++) s += wv[d] * svk[h][d * 8 + e];
            s *= sginv[h][e];
            _Float16 sh = (_Float16)s;
            hi.h8[e] = sh;
            lo.h8[e] = (_Float16)(s - (float)sh);
        }
        *reinterpret_cast<uint4*>(Mhi + ((size_t)b * 256 + tid) * 512 + h * 8) = hi.u;
        *reinterpret_cast<uint4*>(Mlo + ((size_t)b * 256 + tid) * 512 + h * 8) = lo.u;
    }
}

// ---------------------------------------------------------------------------
// K5: 128-px tile, 4 barriers total. Qt_e = QSCALE*g_e*q_e/den (bounded),
// f16; two half-K phases (heads 0..31 from Qf, 32..63 from Qagg), each a
// 2-pass hi/lo f16 MFMA GEMM (256ch x 128px). LDS ~70 KB -> 2 blocks/CU.
// ---------------------------------------------------------------------------
__global__ __launch_bounds__(256) void attn_proj_mfma(
    const float* __restrict__ Qf,      // (B,256,HW) packed q (>=0)
    const float* __restrict__ Qagg,    // (B,256,HW) packed dwconv(q), raw
    const float* __restrict__ stats,   // ksum at [64..71]
    const _Float16* __restrict__ Mhi,  // (B,256,512)
    const _Float16* __restrict__ Mlo,
    const float* __restrict__ scale, const float* __restrict__ bias,
    float* __restrict__ out)           // (B,256,HW)
{
    const int pt  = blockIdx.x * 128;
    const int b   = blockIdx.y;
    const int tid = threadIdx.x;
    const int wv  = tid >> 6, lane = tid & 63;

    __shared__ _Float16 Qt[128][264];     // 67.6 KB half-K [px][k]
    __shared__ float    ksums[64][8];     // 2 KB

    for (int i = tid; i < 512; i += 256)
        ksums[i >> 3][i & 7] = stats[((size_t)b * 64 + (i >> 3)) * 72 + 64 + (i & 7)];
    __syncthreads();

    const int pxl = tid & 127;            // local pixel for Qt build
    const int eg  = (tid >> 7) * 4;       // 4 e's per thread
    const int u = lane & 15, q8 = (lane >> 4) * 8;
    const int quad = lane >> 4;

    floatx4 acc[4][8];
    #pragma unroll
    for (int i = 0; i < 4; i++)
        #pragma unroll
        for (int j = 0; j < 8; j++) acc[i][j] = (floatx4)0.f;

    // ============ phase A: heads 0..31 (q direct from Qf, >=0) ============
    for (int h = 0; h < 32; h++) {
        const float* qp = Qf + ((size_t)b * 256 + h * 8) * HW + pt + pxl;
        float qv[8];
        #pragma unroll
        for (int e = 0; e < 8; e++) qv[e] = qp[(size_t)e * HW];
        float den = EPS_F;
        #pragma unroll
        for (int e = 0; e < 8; e++) den += ksums[h][e] * qv[e];
        float rd = QSCALE / den;
        union { _Float16 h4[4]; uint2 u2; } pk;
        #pragma unroll
        for (int j = 0; j < 4; j++) {
            float g = ksums[h][eg + j] + EPS_F;
            pk.h4[j] = (_Float16)fminf(qv[eg + j] * g * rd, 60000.f);
        }
        *reinterpret_cast<uint2*>(&Qt[pxl][h * 8 + eg]) = pk.u2;
    }
    __syncthreads();

    for (int ks = 0; ks < 8; ks++) {
        half8 ah[4], al[4], bf[8];
        #pragma unroll
        for (int mt = 0; mt < 4; mt++) {
            size_t moff = ((size_t)b * 256 + wv * 64 + mt * 16 + u) * 512 + ks * 32 + q8;
            ah[mt] = *reinterpret_cast<const half8*>(Mhi + moff);
            al[mt] = *reinterpret_cast<const half8*>(Mlo + moff);
        }
        #pragma unroll
        for (int nt = 0; nt < 8; nt++)
            bf[nt] = *reinterpret_cast<const half8*>(&Qt[nt * 16 + u][ks * 32 + q8]);
        #pragma unroll
        for (int mt = 0; mt < 4; mt++)
            #pragma unroll
            for (int nt = 0; nt < 8; nt++) {
                acc[mt][nt] = __builtin_amdgcn_mfma_f32_16x16x32_f16(ah[mt], bf[nt], acc[mt][nt], 0, 0, 0);
                acc[mt][nt] = __builtin_amdgcn_mfma_f32_16x16x32_f16(al[mt], bf[nt], acc[mt][nt], 0, 0, 0);
            }
    }
    __syncthreads();

    // ============ phase B: heads 32..63 (q from Qagg, needs relu) ==========
    for (int h = 32; h < 64; h++) {
        const int hb = h - 32;
        const float* qp = Qagg + ((size_t)b * 256 + hb * 8) * HW + pt + pxl;
        float qv[8];
        #pragma unroll
        for (int e = 0; e < 8; e++) qv[e] = fmaxf(qp[(size_t)e * HW], 0.f);
        float den = EPS_F;
        #pragma unroll
        for (int e = 0; e < 8; e++) den += ksums[h][e] * qv[e];
        float rd = QSCALE / den;
        union { _Float16 h4[4]; uint2 u2; } pk;
        #pragma unroll
        for (int j = 0; j < 4; j++) {
            float g = ksums[h][eg + j] + EPS_F;
            pk.h4[j] = (_Float16)fminf(qv[eg + j] * g * rd, 60000.f);
        }
        *reinterpret_cast<uint2*>(&Qt[pxl][hb * 8 + eg]) = pk.u2;
    }
    __syncthreads();

    for (int ks = 0; ks < 8; ks++) {
        half8 ah[4], al[4], bf[8];
        #pragma unroll
        for (int mt = 0; mt < 4; mt++) {
            size_t moff = ((size_t)b * 256 + wv * 64 + mt * 16 + u) * 512 + 256 + ks * 32 + q8;
            ah[mt] = *reinterpret_cast<const half8*>(Mhi + moff);
            al[mt] = *reinterpret_cast<const half8*>(Mlo + moff);
        }
        #pragma unroll
        for (int nt = 0; nt < 8; nt++)
            bf[nt] = *reinterpret_cast<const half8*>(&Qt[nt * 16 + u][ks * 32 + q8]);
        #pragma unroll
        for (int mt = 0; mt < 4; mt++)
            #pragma unroll
            for (int nt = 0; nt < 8; nt++) {
                acc[mt][nt] = __builtin_amdgcn_mfma_f32_16x16x32_f16(ah[mt], bf[nt], acc[mt][nt], 0, 0, 0);
                acc[mt][nt] = __builtin_amdgcn_mfma_f32_16x16x32_f16(al[mt], bf[nt], acc[mt][nt], 0, 0, 0);
            }
    }

    #pragma unroll
    for (int mt = 0; mt < 4; mt++)
        #pragma unroll
        for (int r = 0; r < 4; r++) {
            int c = wv * 64 + mt * 16 + quad * 4 + r;
            float s = scale[c] * (1.0f / QSCALE);
            float bi = bias[c];
            #pragma unroll
            for (int nt = 0; nt < 8; nt++) {
                int px = pt + nt * 16 + u;
                out[((size_t)b * COUT + c) * HW + px] = fmaxf(acc[mt][nt][r] * s + bi, 0.f);
            }
        }
}

// ---------------------------------------------------------------------------
extern "C" void kernel_launch(void* const* d_in, const int* in_sizes, int n_in,
                              void* d_out, int out_size, void* d_ws, size_t ws_size,
                              hipStream_t stream)
{
    const float* x      = (const float*)d_in[0];
    const float* qkv_w  = (const float*)d_in[1];
    const float* qkv_s  = (const float*)d_in[2];
    const float* qkv_b  = (const float*)d_in[3];
    const float* dw_w   = (const float*)d_in[4];
    const float* dw_b   = (const float*)d_in[5];
    const float* pw_w   = (const float*)d_in[6];
    const float* pw_b   = (const float*)d_in[7];
    const float* proj_w = (const float*)d_in[8];
    const float* proj_s = (const float*)d_in[9];
    const float* proj_b = (const float*)d_in[10];
    float* out = (float*)d_out;

    // ws layout (exactly the PROVEN 192.3 MiB):
    //   [0,128 MiB)    KV f32 — dead after K2/K3; reused: Mhi(4)+Mlo(4)+Qagg(64)
    //   [128,192 MiB)  Qf f32
    //   [192 MiB,+288K) stats
    float*    KV    = (float*)d_ws;
    _Float16* Mhi   = (_Float16*)d_ws;                          // +0
    _Float16* Mlo   = Mhi + (size_t)BATCH * 256 * 512;          // +4 MiB
    float*    Qagg  = (float*)(Mlo + (size_t)BATCH * 256 * 512);// +8 MiB (64 MiB)
    float*    Qf    = KV + (size_t)BATCH * 512 * HW;            // +128 MiB
    float*    stats = Qf + (size_t)BATCH * 256 * HW;            // +192 MiB

    conv_q_f32<<<dim3(HW / 128, 2, BATCH), 256, 0, stream>>>(
        x, qkv_w, qkv_s, qkv_b, Qf);

    conv_kv_mfma<<<dim3(4, 32, BATCH), 256, 0, stream>>>(
        x, qkv_w, qkv_s, qkv_b, KV);

    // zero stats before the atomic-reduce stats kernels
    zero_stats<<<dim3((BATCH * 64 * 72 + 255) / 256), 256, 0, stream>>>(stats);

    attn_stats_direct<<<dim3(32, 4, BATCH), 256, 0, stream>>>(KV, stats);

    attn_stats_dw<<<dim3(32, 2, BATCH), 256, 0, stream>>>(
        KV, dw_w, dw_b, pw_w, pw_b, stats);

    // after K2/K3: KV region dead -> safe to overwrite with Qagg / M
    q_dwconv<<<dim3(32, 2, BATCH), 256, 0, stream>>>(
        Qf, dw_w, dw_b, pw_w, pw_b, Qagg);

    build_M<<<dim3(BATCH), 256, 0, stream>>>(stats, proj_w, Mhi, Mlo);

    attn_proj_mfma<<<dim3(HW / 128, BATCH), 256, 0, stream>>>(
        Qf, Qagg, stats, Mhi, Mlo, proj_s, proj_b, out);
}

// Round 8
// 568.947 us; speedup vs baseline: 1.6904x; 1.2665x over previous
//
#include <hip/hip_runtime.h>

#define HW    4096
#define WIMG  64
#define CIN   256
#define C3    768
#define COUT  256
#define BATCH 16
#define NHB   32
#define EPS_F 1e-5f
#define QSCALE 1024.0f   // pow2: exactly undone in epilogue

typedef __attribute__((ext_vector_type(8))) short    short8;
typedef __attribute__((ext_vector_type(8))) _Float16 half8;
typedef __attribute__((ext_vector_type(4))) float    floatx4;

__device__ inline short f32_to_bf16(float f) {
    unsigned u = __builtin_bit_cast(unsigned, f);
    unsigned r = u + 0x7fffu + ((u >> 16) & 1u);
    return (short)(r >> 16);
}
__device__ inline float bf16_to_f32(short s) {
    return __builtin_bit_cast(float, ((unsigned)(unsigned short)s) << 16);
}

// ---------------------------------------------------------------------------
// K1a: q channels (packed 256) of qkv 1x1 conv, f32 VALU GEMM.
// 128x128 tile, 8x8 per thread (split as {t*4, 64+t*4} for 2-way-free LDS).
// q needs f32 absolute accuracy (eps-denominator cliff).
// Packed c' in [0,256): real C3 channel = (c'>>3)*24 + (c'&7).
// ---------------------------------------------------------------------------
__global__ __launch_bounds__(256) void conv_q_f32(
    const float* __restrict__ in,     // (B, 256, HW)
    const float* __restrict__ w,      // (768, 256)
    const float* __restrict__ scale,
    const float* __restrict__ bias,
    float* __restrict__ Qf)           // (B, 256, HW) packed q
{
    const int pt  = blockIdx.x * 128;
    const int ct  = blockIdx.y * 128;
    const int b   = blockIdx.z;
    const int tid = threadIdx.x;
    const int tx  = tid & 15;         // px groups tx*4 and 64+tx*4
    const int ty  = tid >> 4;         // ch groups ty*4 and 64+ty*4

    __shared__ float Ws[16][128];
    __shared__ float Xs[16][128];

    float acc[8][8] = {};
    const float* xb = in + (size_t)b * CIN * HW + pt;

    for (int k0 = 0; k0 < CIN; k0 += 16) {
        #pragma unroll
        for (int i = 0; i < 8; i++) {
            int idx = tid + i * 256;          // 0..2047
            int c = idx >> 4, k = idx & 15;
            int cp = ct + c;
            int creal = (cp >> 3) * 24 + (cp & 7);
            Ws[k][c] = w[(size_t)creal * CIN + k0 + k];
        }
        #pragma unroll
        for (int i = 0; i < 8; i++) {
            int idx = tid + i * 256;
            int k = idx >> 7, p = idx & 127;
            Xs[k][p] = xb[(size_t)(k0 + k) * HW + p];
        }
        __syncthreads();
        #pragma unroll
        for (int kk = 0; kk < 16; kk++) {
            float4 a0 = *reinterpret_cast<const float4*>(&Ws[kk][ty * 4]);
            float4 a1 = *reinterpret_cast<const float4*>(&Ws[kk][64 + ty * 4]);
            float4 b0 = *reinterpret_cast<const float4*>(&Xs[kk][tx * 4]);
            float4 b1 = *reinterpret_cast<const float4*>(&Xs[kk][64 + tx * 4]);
            float a[8] = {a0.x, a0.y, a0.z, a0.w, a1.x, a1.y, a1.z, a1.w};
            float bb[8] = {b0.x, b0.y, b0.z, b0.w, b1.x, b1.y, b1.z, b1.w};
            #pragma unroll
            for (int i = 0; i < 8; i++)
                #pragma unroll
                for (int j = 0; j < 8; j++)
                    acc[i][j] += a[i] * bb[j];
        }
        __syncthreads();
    }

    #pragma unroll
    for (int i = 0; i < 8; i++) {
        int cp = ct + (i < 4 ? ty * 4 + i : 64 + ty * 4 + (i - 4));
        int creal = (cp >> 3) * 24 + (cp & 7);
        float s = scale[creal];
        float bi = bias[creal];
        float4 v0, v1;
        v0.x = fmaxf(acc[i][0] * s + bi, 0.f);
        v0.y = fmaxf(acc[i][1] * s + bi, 0.f);
        v0.z = fmaxf(acc[i][2] * s + bi, 0.f);
        v0.w = fmaxf(acc[i][3] * s + bi, 0.f);
        v1.x = fmaxf(acc[i][4] * s + bi, 0.f);
        v1.y = fmaxf(acc[i][5] * s + bi, 0.f);
        v1.z = fmaxf(acc[i][6] * s + bi, 0.f);
        v1.w = fmaxf(acc[i][7] * s + bi, 0.f);
        float* dst = Qf + ((size_t)b * 256 + cp) * HW + pt;
        *reinterpret_cast<float4*>(dst + tx * 4)      = v0;
        *reinterpret_cast<float4*>(dst + 64 + tx * 4) = v1;
    }
}

// ---------------------------------------------------------------------------
// K1b: k/v channels (packed 512) via bf16 hi/lo 3-pass MFMA (~f32 accurate).
// Packed c' in [0,512): real = (c'>>4)*24 + 8 + (c'&15). Out f32.
// ---------------------------------------------------------------------------
__global__ __launch_bounds__(256) void conv_kv_mfma(
    const float* __restrict__ x,
    const float* __restrict__ w,
    const float* __restrict__ scale,
    const float* __restrict__ bias,
    float* __restrict__ KV)           // (B, 512, HW) packed k/v, f32
{
    const int ct = blockIdx.x, pt = blockIdx.y, b = blockIdx.z;
    const int tid  = threadIdx.x;
    const int wv   = tid >> 6, lane = tid & 63;
    const int u    = lane & 15, q8 = (lane >> 4) * 8;
    const int chb  = ct * 128 + (wv >> 1) * 64;
    const int pxb  = pt * 128 + (wv & 1) * 64;

    floatx4 acc[4][4];
    #pragma unroll
    for (int i = 0; i < 4; i++)
        #pragma unroll
        for (int j = 0; j < 4; j++) acc[i][j] = (floatx4)0.f;

    for (int kc = 0; kc < 8; kc++) {
        const int k0 = kc * 32 + q8;
        short8 ahi[4], alo[4];
        #pragma unroll
        for (int mt = 0; mt < 4; mt++) {
            int cp = chb + mt * 16 + u;
            int creal = (cp >> 4) * 24 + 8 + (cp & 15);
            const float* wp = w + (size_t)creal * CIN + k0;
            #pragma unroll
            for (int j = 0; j < 8; j++) {
                float f = wp[j];
                short h = f32_to_bf16(f);
                ahi[mt][j] = h;
                alo[mt][j] = f32_to_bf16(f - bf16_to_f32(h));
            }
        }
        short8 bhi[4], blo[4];
        #pragma unroll
        for (int nt = 0; nt < 4; nt++) {
            const float* xp = x + ((size_t)b * CIN + k0) * HW + pxb + nt * 16 + u;
            #pragma unroll
            for (int j = 0; j < 8; j++) {
                float f = xp[(size_t)j * HW];
                short h = f32_to_bf16(f);
                bhi[nt][j] = h;
                blo[nt][j] = f32_to_bf16(f - bf16_to_f32(h));
            }
        }
        #pragma unroll
        for (int mt = 0; mt < 4; mt++)
            #pragma unroll
            for (int nt = 0; nt < 4; nt++) {
                acc[mt][nt] = __builtin_amdgcn_mfma_f32_16x16x32_bf16(ahi[mt], bhi[nt], acc[mt][nt], 0, 0, 0);
                acc[mt][nt] = __builtin_amdgcn_mfma_f32_16x16x32_bf16(ahi[mt], blo[nt], acc[mt][nt], 0, 0, 0);
                acc[mt][nt] = __builtin_amdgcn_mfma_f32_16x16x32_bf16(alo[mt], bhi[nt], acc[mt][nt], 0, 0, 0);
            }
    }

    const int quad = lane >> 4;
    #pragma unroll
    for (int mt = 0; mt < 4; mt++)
        #pragma unroll
        for (int r = 0; r < 4; r++) {
            int cp = chb + mt * 16 + quad * 4 + r;
            int creal = (cp >> 4) * 24 + 8 + (cp & 15);
            float s = scale[creal], bi = bias[creal];
            #pragma unroll
            for (int nt = 0; nt < 4; nt++) {
                int px = pxb + nt * 16 + u;
                KV[((size_t)b * 512 + cp) * HW + px] = fmaxf(acc[mt][nt][r] * s + bi, 0.f);
            }
        }
}

// ---------------------------------------------------------------------------
// K0z: zero the stats region (atomic consumers below; re-entrant per launch).
// ---------------------------------------------------------------------------
__global__ __launch_bounds__(256) void zero_stats(float* __restrict__ stats)
{
    int i = blockIdx.x * 256 + threadIdx.x;
    if (i < BATCH * 64 * 72) stats[i] = 0.f;
}

// ---------------------------------------------------------------------------
// K2 v6: stats heads 0..31 via MFMA GRAM. Lane (c=lane&15, kg=lane>>4)
// streams 8 px of channel c per 32-px step; same short8 is both A-row c and
// B-col c of mfma_f32_16x16x32_bf16 -> D = Gram (16x16); rows 8..15 x cols
// 0..7 = vk. ksum via B=ones MFMA. bf16 hi/lo 3-pass ~f32. No LDS/barriers.
// grid (32 h, 4 ps, 16 b) = 2048 blocks.
// ---------------------------------------------------------------------------
__global__ __launch_bounds__(256) void attn_stats_direct(
    const float* __restrict__ KV,
    float* __restrict__ stats)
{
    const int h = blockIdx.x, ps = blockIdx.y, b = blockIdx.z;
    const int tid = threadIdx.x;
    const int lane = tid & 63, wv = tid >> 6;
    const int c  = lane & 15;
    const int kg = lane >> 4;

    const float* cb = KV + ((size_t)b * 512 + h * 16 + c) * HW
                    + ps * 1024 + wv * 256 + kg * 8;

    floatx4 accg = (floatx4)0.f;     // gram
    floatx4 accs = (floatx4)0.f;     // rowsums (ksum in rows 0..7)
    short8 ones;
    #pragma unroll
    for (int j = 0; j < 8; j++) ones[j] = (short)0x3F80;  // bf16 1.0

    for (int st = 0; st < 8; st++) {
        float4 f0 = *reinterpret_cast<const float4*>(cb + st * 32);
        float4 f1 = *reinterpret_cast<const float4*>(cb + st * 32 + 4);
        float v[8] = {f0.x, f0.y, f0.z, f0.w, f1.x, f1.y, f1.z, f1.w};
        short8 hi, lo;
        #pragma unroll
        for (int j = 0; j < 8; j++) {
            short hh = f32_to_bf16(v[j]);
            hi[j] = hh;
            lo[j] = f32_to_bf16(v[j] - bf16_to_f32(hh));
        }
        accg = __builtin_amdgcn_mfma_f32_16x16x32_bf16(hi, hi, accg, 0, 0, 0);
        accg = __builtin_amdgcn_mfma_f32_16x16x32_bf16(hi, lo, accg, 0, 0, 0);
        accg = __builtin_amdgcn_mfma_f32_16x16x32_bf16(lo, hi, accg, 0, 0, 0);
        accs = __builtin_amdgcn_mfma_f32_16x16x32_bf16(hi, ones, accs, 0, 0, 0);
        accs = __builtin_amdgcn_mfma_f32_16x16x32_bf16(lo, ones, accs, 0, 0, 0);
    }

    // D layout: col = lane&15, row = (lane>>4)*4 + r
    float* sb = stats + ((size_t)b * 64 + h) * 72;
    if (c < 8 && kg >= 2) {           // rows 8..15 (v), cols 0..7 (k)
        #pragma unroll
        for (int r = 0; r < 4; r++)
            atomicAdd(sb + ((kg - 2) * 4 + r) * 8 + c, accg[r]);
    }
    if (c == 0 && kg < 2) {           // ksum rows 0..7, any col -> col 0
        #pragma unroll
        for (int r = 0; r < 4; r++)
            atomicAdd(sb + 64 + kg * 4 + r, accs[r]);
    }
}

// ---------------------------------------------------------------------------
// K3 v7: stats heads 32..63 = rolling-window 5x5 dwconv fused with MFMA GRAM.
// Each input row is loaded ONCE (12 rows/strip) and scattered into the <=5
// live output-row accumulators out[5][8] (rotating slots, full unroll ->
// compile-time indices). When input li lands, output li-4 completes ->
// affine -> relu(k) -> bf16 hi/lo -> 5 Gram/ksum MFMAs -> slot reset.
// No LDS, no barriers. grid (32 hp, 2 ysb, 16 b) = 1024 blocks.
// ---------------------------------------------------------------------------
__global__ __launch_bounds__(256) void attn_stats_dw(
    const float* __restrict__ KV,
    const float* __restrict__ dww, const float* __restrict__ dwb,
    const float* __restrict__ pww, const float* __restrict__ pwb,
    float* __restrict__ stats)
{
    const int hp = blockIdx.x, ysb = blockIdx.y, b = blockIdx.z;
    const int tid = threadIdx.x;
    const int lane = tid & 63, wv = tid >> 6;
    const int c  = lane & 15;
    const int kg = lane >> 4;
    const int creal = hp * 24 + 8 + c;

    float wt[25];
    #pragma unroll
    for (int i = 0; i < 25; i++) wt[i] = dww[creal * 25 + i];
    const float pw = pww[creal];
    const float pb = pw * dwb[creal] + pwb[creal];

    const float* cb = KV + ((size_t)b * 512 + hp * 16 + c) * HW;
    const int ybase = ysb * 32 + wv * 8;

    floatx4 accg = (floatx4)0.f;
    floatx4 accs = (floatx4)0.f;
    short8 ones;
    #pragma unroll
    for (int j = 0; j < 8; j++) ones[j] = (short)0x3F80;

    #pragma unroll
    for (int xh = 0; xh < 2; xh++) {
        const int x0 = xh * 32 + kg * 8;
        const float mL = (x0 == 0)  ? 0.f : 1.f;
        const float mR = (x0 == 56) ? 0.f : 1.f;
        const int colL = (x0 == 0)  ? 0  : x0 - 4;
        const int colR = (x0 == 56) ? 56 : x0 + 8;

        float out[5][8] = {};
        #pragma unroll
        for (int li = 0; li < 12; li++) {
            const int ry = ybase + li - 2;
            float4 Q0 = {0,0,0,0}, Q1 = {0,0,0,0}, Q2 = {0,0,0,0}, Q3 = {0,0,0,0};
            if (ry >= 0 && ry < WIMG) {          // wave-uniform
                const float* rp = cb + ry * WIMG;
                Q0 = *reinterpret_cast<const float4*>(rp + colL);
                Q1 = *reinterpret_cast<const float4*>(rp + x0);
                Q2 = *reinterpret_cast<const float4*>(rp + x0 + 4);
                Q3 = *reinterpret_cast<const float4*>(rp + colR);
            }
            float win[12] = {Q0.z * mL, Q0.w * mL,
                             Q1.x, Q1.y, Q1.z, Q1.w,
                             Q2.x, Q2.y, Q2.z, Q2.w,
                             Q3.x * mR, Q3.y * mR};
            // scatter into live output rows lo = li-4..li
            #pragma unroll
            for (int rr = 0; rr < 5; rr++) {
                const int lo = li - rr;
                if (lo >= 0 && lo < 8) {
                    #pragma unroll
                    for (int kx = 0; kx < 5; kx++) {
                        float w5 = wt[rr * 5 + kx];
                        #pragma unroll
                        for (int j = 0; j < 8; j++)
                            out[lo % 5][j] += w5 * win[j + kx];
                    }
                }
            }
            // finalize completed output row lo = li-4
            const int lod = li - 4;
            if (lod >= 0 && lod < 8) {
                short8 hib, lob;
                #pragma unroll
                for (int j = 0; j < 8; j++) {
                    float v = out[lod % 5][j] * pw + pb;
                    float vr = fmaxf(v, 0.f);
                    v = (c < 8) ? vr : v;        // relu k-channels only
                    short hh = f32_to_bf16(v);
                    hib[j] = hh;
                    lob[j] = f32_to_bf16(v - bf16_to_f32(hh));
                }
                accg = __builtin_amdgcn_mfma_f32_16x16x32_bf16(hib, hib, accg, 0, 0, 0);
                accg = __builtin_amdgcn_mfma_f32_16x16x32_bf16(hib, lob, accg, 0, 0, 0);
                accg = __builtin_amdgcn_mfma_f32_16x16x32_bf16(lob, hib, accg, 0, 0, 0);
                accs = __builtin_amdgcn_mfma_f32_16x16x32_bf16(hib, ones, accs, 0, 0, 0);
                accs = __builtin_amdgcn_mfma_f32_16x16x32_bf16(lob, ones, accs, 0, 0, 0);
                #pragma unroll
                for (int j = 0; j < 8; j++) out[lod % 5][j] = 0.f;
            }
        }
    }

    float* sb = stats + ((size_t)b * 64 + 32 + hp) * 72;
    if (c < 8 && kg >= 2) {
        #pragma unroll
        for (int r = 0; r < 4; r++)
            atomicAdd(sb + ((kg - 2) * 4 + r) * 8 + c, accg[r]);
    }
    if (c == 0 && kg < 2) {
        #pragma unroll
        for (int r = 0; r < 4; r++)
            atomicAdd(sb + 64 + kg * 4 + r, accs[r]);
    }
}

// ---------------------------------------------------------------------------
// K3b v7: Qagg = rolling-window 5x5 dwconv + affine of q channels; each input
// row loaded once, out[5][8] rotating slots, finalize -> 2x float4 store.
// Lane (c=lane&7, g=lane>>3) covers 8 px of channel c; wave = full 64-px row
// x 8 channels. grid (32 hb, 2 ysb, 16 b) = 1024 blocks. Raw out (relu K5).
// ---------------------------------------------------------------------------
__global__ __launch_bounds__(256) void q_dwconv(
    const float* __restrict__ Qf,     // (B,256,HW) packed q
    const float* __restrict__ dww, const float* __restrict__ dwb,
    const float* __restrict__ pww, const float* __restrict__ pwb,
    float* __restrict__ Qagg)         // (B,256,HW) packed dwconv(q)
{
    const int hb = blockIdx.x, ysb = blockIdx.y, b = blockIdx.z;
    const int tid = threadIdx.x;
    const int lane = tid & 63, wv = tid >> 6;
    const int c = lane & 7;
    const int g = lane >> 3;          // 0..7
    const int x0 = g * 8;
    const int creal = hb * 24 + c;

    float wt[25];
    #pragma unroll
    for (int i = 0; i < 25; i++) wt[i] = dww[creal * 25 + i];
    const float pw = pww[creal];
    const float pb = pw * dwb[creal] + pwb[creal];

    const float mL = (x0 == 0)  ? 0.f : 1.f;
    const float mR = (x0 == 56) ? 0.f : 1.f;
    const int colL = (x0 == 0)  ? 0  : x0 - 4;
    const int colR = (x0 == 56) ? 56 : x0 + 8;

    const float* cbase = Qf   + ((size_t)b * 256 + hb * 8 + c) * HW;
    float*       obase = Qagg + ((size_t)b * 256 + hb * 8 + c) * HW;
    const int ybase = ysb * 32 + wv * 8;

    float out[5][8] = {};
    #pragma unroll
    for (int li = 0; li < 12; li++) {
        const int ry = ybase + li - 2;
        float4 Q0 = {0,0,0,0}, Q1 = {0,0,0,0}, Q2 = {0,0,0,0}, Q3 = {0,0,0,0};
        if (ry >= 0 && ry < WIMG) {
            const float* rp = cbase + ry * WIMG;
            Q0 = *reinterpret_cast<const float4*>(rp + colL);
            Q1 = *reinterpret_cast<const float4*>(rp + x0);
            Q2 = *reinterpret_cast<const float4*>(rp + x0 + 4);
            Q3 = *reinterpret_cast<const float4*>(rp + colR);
        }
        float win[12] = {Q0.z * mL, Q0.w * mL,
                         Q1.x, Q1.y, Q1.z, Q1.w,
                         Q2.x, Q2.y, Q2.z, Q2.w,
                         Q3.x * mR, Q3.y * mR};
        #pragma unroll
        for (int rr = 0; rr < 5; rr++) {
            const int lo = li - rr;
            if (lo >= 0 && lo < 8) {
                #pragma unroll
                for (int kx = 0; kx < 5; kx++) {
                    float w5 = wt[rr * 5 + kx];
                    #pragma unroll
                    for (int j = 0; j < 8; j++)
                        out[lo % 5][j] += w5 * win[j + kx];
                }
            }
        }
        const int lod = li - 4;
        if (lod >= 0 && lod < 8) {
            float4 o0 = {out[lod % 5][0] * pw + pb, out[lod % 5][1] * pw + pb,
                         out[lod % 5][2] * pw + pb, out[lod % 5][3] * pw + pb};
            float4 o1 = {out[lod % 5][4] * pw + pb, out[lod % 5][5] * pw + pb,
                         out[lod % 5][6] * pw + pb, out[lod % 5][7] * pw + pb};
            float* dst = obase + (ybase + lod) * WIMG + x0;
            *reinterpret_cast<float4*>(dst)     = o0;
            *reinterpret_cast<float4*>(dst + 4) = o1;
            #pragma unroll
            for (int j = 0; j < 8; j++) out[lod % 5][j] = 0.f;
        }
    }
}

// ---------------------------------------------------------------------------
// K4 v2: fold proj weights with vk, COLUMN-RESCALED by g_e = ksum_e + eps.
// Parallelized over head-groups: grid (8 hg, 16 b) = 128 blocks (was 16).
// Each block: 8 heads x 256 channels; svk[8][64]+sginv[8][8] staged (2.3 KB);
// thread = channel, 8 h iterations, contiguous 64-float projw slice.
// Identical math/output layout to v1.
// ---------------------------------------------------------------------------
__global__ __launch_bounds__(256) void build_M(
    const float* __restrict__ stats,   // (B,64,72)
    const float* __restrict__ projw,   // (256,512)
    _Float16* __restrict__ Mhi,        // (B,256,512)
    _Float16* __restrict__ Mlo)
{
    const int hg = blockIdx.x;         // head group (8 heads)
    const int b  = blockIdx.y;
    const int tid = threadIdx.x;

    __shared__ float svk[8][64];
    __shared__ float sginv[8][8];

    for (int i = tid; i < 8 * 64; i += 256) {
        int h = i >> 6;
        svk[h][i & 63] = stats[((size_t)b * 64 + hg * 8 + h) * 72 + (i & 63)];
    }
    if (tid < 64)
        sginv[tid >> 3][tid & 7] =
            1.0f / (stats[((size_t)b * 64 + hg * 8 + (tid >> 3)) * 72 + 64 + (tid & 7)] + EPS_F);
    __syncthreads();

    const float* wr = projw + (size_t)tid * 512 + hg * 64;
    #pragma unroll
    for (int hh = 0; hh < 8; hh++) {
        float wv[8];
        float4 a0 = *reinterpret_cast<const float4*>(wr + hh * 8);
        float4 a1 = *reinterpret_cast<const float4*>(wr + hh * 8 + 4);
        wv[0]=a0.x; wv[1]=a0.y; wv[2]=a0.z; wv[3]=a0.w;
        wv[4]=a1.x; wv[5]=a1.y; wv[6]=a1.z; wv[7]=a1.w;
        union { _Float16 h8[8]; uint4 u; } hi, lo;
        #pragma unroll
        for (int e = 0; e < 8; e++) {
            float s = 0.f;
            #pragma unroll
            for (int d = 0; d < 8; d++) s += wv[d] * svk[hh][d * 8 + e];
            s *= sginv[hh][e];
            _Float16 sh = (_Float16)s;
            hi.h8[e] = sh;
            lo.h8[e] = (_Float16)(s - (float)sh);
        }
        size_t off = ((size_t)b * 256 + tid) * 512 + hg * 64 + hh * 8;
        *reinterpret_cast<uint4*>(Mhi + off) = hi.u;
        *reinterpret_cast<uint4*>(Mlo + off) = lo.u;
    }
}

// ---------------------------------------------------------------------------
// K5: 128-px tile, 4 barriers total. Qt_e = QSCALE*g_e*q_e/den (bounded),
// f16; two half-K phases (heads 0..31 from Qf, 32..63 from Qagg), each a
// 2-pass hi/lo f16 MFMA GEMM (256ch x 128px). LDS ~70 KB -> 2 blocks/CU.
// ---------------------------------------------------------------------------
__global__ __launch_bounds__(256) void attn_proj_mfma(
    const float* __restrict__ Qf,      // (B,256,HW) packed q (>=0)
    const float* __restrict__ Qagg,    // (B,256,HW) packed dwconv(q), raw
    const float* __restrict__ stats,   // ksum at [64..71]
    const _Float16* __restrict__ Mhi,  // (B,256,512)
    const _Float16* __restrict__ Mlo,
    const float* __restrict__ scale, const float* __restrict__ bias,
    float* __restrict__ out)           // (B,256,HW)
{
    const int pt  = blockIdx.x * 128;
    const int b   = blockIdx.y;
    const int tid = threadIdx.x;
    const int wv  = tid >> 6, lane = tid & 63;

    __shared__ _Float16 Qt[128][264];     // 67.6 KB half-K [px][k]
    __shared__ float    ksums[64][8];     // 2 KB

    for (int i = tid; i < 512; i += 256)
        ksums[i >> 3][i & 7] = stats[((size_t)b * 64 + (i >> 3)) * 72 + 64 + (i & 7)];
    __syncthreads();

    const int pxl = tid & 127;            // local pixel for Qt build
    const int eg  = (tid >> 7) * 4;       // 4 e's per thread
    const int u = lane & 15, q8 = (lane >> 4) * 8;
    const int quad = lane >> 4;

    floatx4 acc[4][8];
    #pragma unroll
    for (int i = 0; i < 4; i++)
        #pragma unroll
        for (int j = 0; j < 8; j++) acc[i][j] = (floatx4)0.f;

    // ============ phase A: heads 0..31 (q direct from Qf, >=0) ============
    for (int h = 0; h < 32; h++) {
        const float* qp = Qf + ((size_t)b * 256 + h * 8) * HW + pt + pxl;
        float qv[8];
        #pragma unroll
        for (int e = 0; e < 8; e++) qv[e] = qp[(size_t)e * HW];
        float den = EPS_F;
        #pragma unroll
        for (int e = 0; e < 8; e++) den += ksums[h][e] * qv[e];
        float rd = QSCALE / den;
        union { _Float16 h4[4]; uint2 u2; } pk;
        #pragma unroll
        for (int j = 0; j < 4; j++) {
            float g = ksums[h][eg + j] + EPS_F;
            pk.h4[j] = (_Float16)fminf(qv[eg + j] * g * rd, 60000.f);
        }
        *reinterpret_cast<uint2*>(&Qt[pxl][h * 8 + eg]) = pk.u2;
    }
    __syncthreads();

    for (int ks = 0; ks < 8; ks++) {
        half8 ah[4], al[4], bf[8];
        #pragma unroll
        for (int mt = 0; mt < 4; mt++) {
            size_t moff = ((size_t)b * 256 + wv * 64 + mt * 16 + u) * 512 + ks * 32 + q8;
            ah[mt] = *reinterpret_cast<const half8*>(Mhi + moff);
            al[mt] = *reinterpret_cast<const half8*>(Mlo + moff);
        }
        #pragma unroll
        for (int nt = 0; nt < 8; nt++)
            bf[nt] = *reinterpret_cast<const half8*>(&Qt[nt * 16 + u][ks * 32 + q8]);
        #pragma unroll
        for (int mt = 0; mt < 4; mt++)
            #pragma unroll
            for (int nt = 0; nt < 8; nt++) {
                acc[mt][nt] = __builtin_amdgcn_mfma_f32_16x16x32_f16(ah[mt], bf[nt], acc[mt][nt], 0, 0, 0);
                acc[mt][nt] = __builtin_amdgcn_mfma_f32_16x16x32_f16(al[mt], bf[nt], acc[mt][nt], 0, 0, 0);
            }
    }
    __syncthreads();

    // ============ phase B: heads 32..63 (q from Qagg, needs relu) ==========
    for (int h = 32; h < 64; h++) {
        const int hb = h - 32;
        const float* qp = Qagg + ((size_t)b * 256 + hb * 8) * HW + pt + pxl;
        float qv[8];
        #pragma unroll
        for (int e = 0; e < 8; e++) qv[e] = fmaxf(qp[(size_t)e * HW], 0.f);
        float den = EPS_F;
        #pragma unroll
        for (int e = 0; e < 8; e++) den += ksums[h][e] * qv[e];
        float rd = QSCALE / den;
        union { _Float16 h4[4]; uint2 u2; } pk;
        #pragma unroll
        for (int j = 0; j < 4; j++) {
            float g = ksums[h][eg + j] + EPS_F;
            pk.h4[j] = (_Float16)fminf(qv[eg + j] * g * rd, 60000.f);
        }
        *reinterpret_cast<uint2*>(&Qt[pxl][hb * 8 + eg]) = pk.u2;
    }
    __syncthreads();

    for (int ks = 0; ks < 8; ks++) {
        half8 ah[4], al[4], bf[8];
        #pragma unroll
        for (int mt = 0; mt < 4; mt++) {
            size_t moff = ((size_t)b * 256 + wv * 64 + mt * 16 + u) * 512 + 256 + ks * 32 + q8;
            ah[mt] = *reinterpret_cast<const half8*>(Mhi + moff);
            al[mt] = *reinterpret_cast<const half8*>(Mlo + moff);
        }
        #pragma unroll
        for (int nt = 0; nt < 8; nt++)
            bf[nt] = *reinterpret_cast<const half8*>(&Qt[nt * 16 + u][ks * 32 + q8]);
        #pragma unroll
        for (int mt = 0; mt < 4; mt++)
            #pragma unroll
            for (int nt = 0; nt < 8; nt++) {
                acc[mt][nt] = __builtin_amdgcn_mfma_f32_16x16x32_f16(ah[mt], bf[nt], acc[mt][nt], 0, 0, 0);
                acc[mt][nt] = __builtin_amdgcn_mfma_f32_16x16x32_f16(al[mt], bf[nt], acc[mt][nt], 0, 0, 0);
            }
    }

    #pragma unroll
    for (int mt = 0; mt < 4; mt++)
        #pragma unroll
        for (int r = 0; r < 4; r++) {
            int c = wv * 64 + mt * 16 + quad * 4 + r;
            float s = scale[c] * (1.0f / QSCALE);
            float bi = bias[c];
            #pragma unroll
            for (int nt = 0; nt < 8; nt++) {
                int px = pt + nt * 16 + u;
                out[((size_t)b * COUT + c) * HW + px] = fmaxf(acc[mt][nt][r] * s + bi, 0.f);
            }
        }
}

// ---------------------------------------------------------------------------
extern "C" void kernel_launch(void* const* d_in, const int* in_sizes, int n_in,
                              void* d_out, int out_size, void* d_ws, size_t ws_size,
                              hipStream_t stream)
{
    const float* x      = (const float*)d_in[0];
    const float* qkv_w  = (const float*)d_in[1];
    const float* qkv_s  = (const float*)d_in[2];
    const float* qkv_b  = (const float*)d_in[3];
    const float* dw_w   = (const float*)d_in[4];
    const float* dw_b   = (const float*)d_in[5];
    const float* pw_w   = (const float*)d_in[6];
    const float* pw_b   = (const float*)d_in[7];
    const float* proj_w = (const float*)d_in[8];
    const float* proj_s = (const float*)d_in[9];
    const float* proj_b = (const float*)d_in[10];
    float* out = (float*)d_out;

    // ws layout (exactly the PROVEN 192.3 MiB):
    //   [0,128 MiB)    KV f32 — dead after K2/K3; reused: Mhi(4)+Mlo(4)+Qagg(64)
    //   [128,192 MiB)  Qf f32
    //   [192 MiB,+288K) stats
    float*    KV    = (float*)d_ws;
    _Float16* Mhi   = (_Float16*)d_ws;                          // +0
    _Float16* Mlo   = Mhi + (size_t)BATCH * 256 * 512;          // +4 MiB
    float*    Qagg  = (float*)(Mlo + (size_t)BATCH * 256 * 512);// +8 MiB (64 MiB)
    float*    Qf    = KV + (size_t)BATCH * 512 * HW;            // +128 MiB
    float*    stats = Qf + (size_t)BATCH * 256 * HW;            // +192 MiB

    conv_q_f32<<<dim3(HW / 128, 2, BATCH), 256, 0, stream>>>(
        x, qkv_w, qkv_s, qkv_b, Qf);

    conv_kv_mfma<<<dim3(4, 32, BATCH), 256, 0, stream>>>(
        x, qkv_w, qkv_s, qkv_b, KV);

    // zero stats before the atomic-reduce stats kernels
    zero_stats<<<dim3((BATCH * 64 * 72 + 255) / 256), 256, 0, stream>>>(stats);

    attn_stats_direct<<<dim3(32, 4, BATCH), 256, 0, stream>>>(KV, stats);

    attn_stats_dw<<<dim3(32, 2, BATCH), 256, 0, stream>>>(
        KV, dw_w, dw_b, pw_w, pw_b, stats);

    // after K2/K3: KV region dead -> safe to overwrite with Qagg / M
    q_dwconv<<<dim3(32, 2, BATCH), 256, 0, stream>>>(
        Qf, dw_w, dw_b, pw_w, pw_b, Qagg);

    build_M<<<dim3(8, BATCH), 256, 0, stream>>>(stats, proj_w, Mhi, Mlo);

    attn_proj_mfma<<<dim3(HW / 128, BATCH), 256, 0, stream>>>(
        Qf, Qagg, stats, Mhi, Mlo, proj_s, proj_b, out);
}